// Round 2
// baseline (898.041 us; speedup 1.0000x reference)
//
#include <hip/hip_runtime.h>
#include <hip/hip_bf16.h>

// CCAttention pipeline on MI355X. Inputs/outputs fp32 (per reference setup),
// internal compute bf16 MFMA, NHWC layout.
// B=2, CIN=2048, CINT=512, CQK=64, H=W=96, S=9216, NG=32 (16 ch/group).

typedef __bf16 bf8_t __attribute__((ext_vector_type(8)));
typedef float f32x4 __attribute__((ext_vector_type(4)));

union I4B8 { int4 i; bf8_t b; };

// ---------------------------------------------------------------- casts
__global__ __launch_bounds__(256) void cast_f32_bf16_k(const float* s, __bf16* d, int n8) {
  int i = blockIdx.x * 256 + threadIdx.x;
  if (i >= n8) return;
  const float4* p = (const float4*)(s + (long long)i * 8);
  float4 a = p[0], b = p[1];
  I4B8 u;
  u.b[0] = (__bf16)a.x; u.b[1] = (__bf16)a.y; u.b[2] = (__bf16)a.z; u.b[3] = (__bf16)a.w;
  u.b[4] = (__bf16)b.x; u.b[5] = (__bf16)b.y; u.b[6] = (__bf16)b.z; u.b[7] = (__bf16)b.w;
  *(int4*)(d + (long long)i * 8) = u.i;
}

__global__ __launch_bounds__(256) void reorder_w_k(const float* w, __bf16* wr) {
  int idx = blockIdx.x * 256 + threadIdx.x;           // 512*4608 total
  if (idx >= 512 * 4608) return;
  int k = idx % 4608, o = idx / 4608;
  int dydx = k / 512, c = k % 512;
  wr[idx] = (__bf16)w[(o * 512 + c) * 9 + dydx];
}

// x (B,2048,96,96) f32 NCHW -> xt (B,9216,2048) bf16 NHWC. 64x64 tiles via LDS.
__global__ __launch_bounds__(256) void transpose_x_k(const float* x, __bf16* xt) {
  __shared__ __bf16 l[64 * 66];                       // elem(c,s) at c*66+s
  int c0 = blockIdx.x * 64, s0 = blockIdx.y * 64, b = blockIdx.z;
  int t = threadIdx.x;
#pragma unroll
  for (int i = 0; i < 2; i++) {
    int slot = t + i * 256;
    int cl = slot >> 3, sch = slot & 7;
    const float* src = x + ((long long)(b * 2048 + c0 + cl)) * 9216 + s0 + sch * 8;
    float4 a = *(const float4*)src, bb = *(const float4*)(src + 4);
    __bf16* dst = &l[cl * 66 + sch * 8];
    dst[0] = (__bf16)a.x; dst[1] = (__bf16)a.y; dst[2] = (__bf16)a.z; dst[3] = (__bf16)a.w;
    dst[4] = (__bf16)bb.x; dst[5] = (__bf16)bb.y; dst[6] = (__bf16)bb.z; dst[7] = (__bf16)bb.w;
  }
  __syncthreads();
#pragma unroll
  for (int i = 0; i < 2; i++) {
    int slot = t + i * 256;
    int sl = slot >> 3, cch = slot & 7;
    I4B8 u;
#pragma unroll
    for (int j = 0; j < 8; j++) u.b[j] = l[(cch * 8 + j) * 66 + sl];
    *(int4*)(xt + ((long long)(b * 9216 + s0 + sl)) * 2048 + c0 + cch * 8) = u.i;
  }
}

// zero-pad NHWC bf16: pad[b][98][98][512]
__global__ __launch_bounds__(256) void pad_k(const __bf16* y, __bf16* pout) {
  long long idx = (long long)blockIdx.x * 256 + threadIdx.x;  // 2*98*98*64 chunks
  int cch = (int)(idx & 63);
  long long r = idx >> 6;
  int ww = (int)(r % 98);
  long long r2 = r / 98;
  int hh = (int)(r2 % 98);
  int b = (int)(r2 / 98);
  int4 v = make_int4(0, 0, 0, 0);
  if (hh >= 1 && hh <= 96 && ww >= 1 && ww <= 96)
    v = *(const int4*)(y + ((long long)(b * 9216 + (hh - 1) * 96 + (ww - 1))) * 512 + cch * 8);
  *(int4*)(pout + r * 512 + cch * 8) = v;
}

// ---------------------------------------------------------------- generic GEMM
// C[M,N] = A[M,K] * B^T ; A rows K-contig (stride sAr), BMODE0: B is N x K rows
// (stride sBr, K-contig); BMODE1: B source is K x N rows (stride sBr, N-contig),
// transposed into LDS during staging. Batched via blockIdx.z -> (z1,z2).
struct GemmP {
  const __bf16 *A, *B;
  __bf16* C;
  long long sAr, sAb1, sAb2;
  long long sBr, sBb1, sBb2;
  long long sCr, sCb1, sCb2;
  int M, N, K, bdiv, mode;  // mode: 0 plain, 1 +bias[n], 2 gamma*(tmp+acc)+res
  const float* bias;
  const __bf16 *tmp, *res;
  const float* gma;
};

template <int BMODE>
__global__ __launch_bounds__(256) void gemm_bt_k(GemmP p) {
  __shared__ __attribute__((aligned(16))) __bf16 lA[128 * 64];
  __shared__ __attribute__((aligned(16))) __bf16 lB[128 * 64];
  const int t = threadIdx.x;
  const int z = blockIdx.z;
  const int z1 = z / p.bdiv, z2 = z % p.bdiv;
  const __bf16* A = p.A + (long long)z1 * p.sAb1 + (long long)z2 * p.sAb2;
  const __bf16* B = p.B + (long long)z1 * p.sBb1 + (long long)z2 * p.sBb2;
  const int m0 = blockIdx.y * 128, n0 = blockIdx.x * 128;
  const int lane = t & 63, wave = t >> 6;
  const int wm = (wave >> 1) * 64, wn = (wave & 1) * 64;
  const int l15 = lane & 15, l4 = lane >> 4;
  f32x4 acc[4][4];
#pragma unroll
  for (int i = 0; i < 4; i++)
#pragma unroll
    for (int j = 0; j < 4; j++) acc[i][j] = f32x4{0.f, 0.f, 0.f, 0.f};

  int arow[4], brow[4];
#pragma unroll
  for (int i = 0; i < 4; i++) {
    int slot = t + i * 256;
    int r = slot >> 3;
    arow[i] = min(m0 + r, p.M - 1);
    brow[i] = min(n0 + r, p.N - 1);
  }
  for (int kb = 0; kb < p.K; kb += 64) {
#pragma unroll
    for (int i = 0; i < 4; i++) {  // A: 128 rows x 8 chunks of 8
      int slot = t + i * 256;
      int r = slot >> 3, c = slot & 7;
      int gk = kb + c * 8;
      int4 v = make_int4(0, 0, 0, 0);
      if (gk < p.K) v = *(const int4*)(A + (long long)arow[i] * p.sAr + gk);
      *(int4*)&lA[r * 64 + (((c + r) & 7) << 3)] = v;
    }
    if (BMODE == 0) {
#pragma unroll
      for (int i = 0; i < 4; i++) {
        int slot = t + i * 256;
        int r = slot >> 3, c = slot & 7;
        int gk = kb + c * 8;
        int4 v = make_int4(0, 0, 0, 0);
        if (gk < p.K) v = *(const int4*)(B + (long long)brow[i] * p.sBr + gk);
        *(int4*)&lB[r * 64 + (((c + r) & 7) << 3)] = v;
      }
    } else {
#pragma unroll
      for (int i = 0; i < 4; i++) {  // B source rows = k, transpose-scatter into lB[n][k]
        int slot = t + i * 256;
        int kl = slot & 63, cch = slot >> 6;  // cch 0..15 (chunks of 8 n's)
        int gk = kb + kl;
        I4B8 u;
        u.i = make_int4(0, 0, 0, 0);
        if (gk < p.K) u.i = *(const int4*)(B + (long long)gk * p.sBr + n0 + cch * 8);
#pragma unroll
        for (int j = 0; j < 8; j++) {
          int n = cch * 8 + j;
          lB[n * 64 + ((((kl >> 3) + n) & 7) << 3) + (kl & 7)] = u.b[j];
        }
      }
    }
    __syncthreads();
#pragma unroll
    for (int kk = 0; kk < 2; kk++) {
      bf8_t af[4], bfr[4];
      int cch = kk * 4 + l4;
#pragma unroll
      for (int mt = 0; mt < 4; mt++) {
        int r = wm + mt * 16 + l15;
        af[mt] = *(bf8_t*)&lA[r * 64 + (((cch + r) & 7) << 3)];
      }
#pragma unroll
      for (int nt = 0; nt < 4; nt++) {
        int r = wn + nt * 16 + l15;
        bfr[nt] = *(bf8_t*)&lB[r * 64 + (((cch + r) & 7) << 3)];
      }
#pragma unroll
      for (int mt = 0; mt < 4; mt++)
#pragma unroll
        for (int nt = 0; nt < 4; nt++)
          acc[mt][nt] = __builtin_amdgcn_mfma_f32_16x16x32_bf16(af[mt], bfr[nt], acc[mt][nt], 0, 0, 0);
    }
    __syncthreads();
  }
  // epilogue
  long long coff = (long long)z1 * p.sCb1 + (long long)z2 * p.sCb2;
  float g = (p.mode == 2) ? *p.gma : 0.f;
#pragma unroll
  for (int nt = 0; nt < 4; nt++) {
    int col = n0 + wn + nt * 16 + l15;
    if (col >= p.N) continue;
    float bv = (p.mode == 1) ? p.bias[col] : 0.f;
#pragma unroll
    for (int mt = 0; mt < 4; mt++) {
      int row0 = m0 + wm + mt * 16 + (l4 << 2);
#pragma unroll
      for (int r = 0; r < 4; r++) {
        int row = row0 + r;
        if (row >= p.M) continue;
        long long off = coff + (long long)row * p.sCr + col;
        float v = acc[mt][nt][r];
        if (p.mode == 2)
          v = g * ((float)p.tmp[off] + v) + (float)p.res[off];
        else
          v += bv;
        p.C[off] = (__bf16)v;
      }
    }
  }
}

// ---------------------------------------------------------------- scores
// mode 0: per-(b,w=f) e_h[h,i] = q[:,h,w].k[:,i,w], diag i==h -> -inf
// mode 1: per-(b,h=f) e_w[w,j]
__global__ __launch_bounds__(384) void cc_scores_k(const __bf16* q, const __bf16* k, float* attnf) {
  __shared__ __attribute__((aligned(16))) __bf16 Qs[96 * 64];
  __shared__ __attribute__((aligned(16))) __bf16 Ks[96 * 64];
  int bfi = blockIdx.x;
  int b = bfi / 96, f = bfi % 96;
  int mode = blockIdx.y;
  long long base = (mode == 0) ? ((long long)(b * 9216 + f)) * 64 : ((long long)(b * 9216 + f * 96)) * 64;
  long long rstr = (mode == 0) ? 96 * 64 : 64;
  int t = threadIdx.x;
#pragma unroll
  for (int i = 0; i < 2; i++) {
    int slot = t + i * 384;
    int r = slot >> 3, c = slot & 7;
    int sw = ((c + r) & 7) << 3;
    *(int4*)&Qs[r * 64 + sw] = *(const int4*)(q + base + (long long)r * rstr + c * 8);
    *(int4*)&Ks[r * 64 + sw] = *(const int4*)(k + base + (long long)r * rstr + c * 8);
  }
  __syncthreads();
  int lane = t & 63, wave = t >> 6;
  int l15 = lane & 15, l4 = lane >> 4;
  f32x4 acc[6];
#pragma unroll
  for (int i = 0; i < 6; i++) acc[i] = f32x4{0.f, 0.f, 0.f, 0.f};
#pragma unroll
  for (int kk = 0; kk < 2; kk++) {
    int ar = wave * 16 + l15;
    int cch = kk * 4 + l4;
    bf8_t af = *(bf8_t*)&Qs[ar * 64 + (((cch + ar) & 7) << 3)];
#pragma unroll
    for (int nt = 0; nt < 6; nt++) {
      int br = nt * 16 + l15;
      bf8_t bfr = *(bf8_t*)&Ks[br * 64 + (((cch + br) & 7) << 3)];
      acc[nt] = __builtin_amdgcn_mfma_f32_16x16x32_bf16(af, bfr, acc[nt], 0, 0, 0);
    }
  }
#pragma unroll
  for (int nt = 0; nt < 6; nt++) {
#pragma unroll
    for (int r = 0; r < 4; r++) {
      int m = wave * 16 + (l4 << 2) + r;
      int n = nt * 16 + l15;
      float v = acc[nt][r];
      long long off;
      if (mode == 0) {
        if (n == m) v = -__builtin_inff();
        off = ((long long)((b * 96 + m) * 96 + f)) * 192 + n;
      } else {
        off = ((long long)((b * 96 + f) * 96 + m)) * 192 + 96 + n;
      }
      attnf[off] = v;
    }
  }
}

__global__ __launch_bounds__(256) void cc_softmax_k(const float* attnf, __bf16* attnb) {
  int wave = threadIdx.x >> 6, lane = threadIdx.x & 63;
  long long row = (long long)blockIdx.x * 4 + wave;
  const float* src = attnf + row * 192;
  float e0 = src[lane], e1 = src[lane + 64], e2 = src[lane + 128];
  float m = fmaxf(e0, fmaxf(e1, e2));
#pragma unroll
  for (int o = 32; o; o >>= 1) m = fmaxf(m, __shfl_xor(m, o));
  e0 = __expf(e0 - m);
  e1 = __expf(e1 - m);
  e2 = __expf(e2 - m);
  float s = e0 + e1 + e2;
#pragma unroll
  for (int o = 32; o; o >>= 1) s += __shfl_xor(s, o);
  float inv = 1.f / s;
  __bf16* dst = attnb + row * 192;
  dst[lane] = (__bf16)(e0 * inv);
  dst[lane + 64] = (__bf16)(e1 * inv);
  dst[lane + 128] = (__bf16)(e2 * inv);
}

// ---------------------------------------------------------------- conv3x3 implicit GEMM
__global__ __launch_bounds__(256) void conv3_gemm_k(const __bf16* pin, const __bf16* wr, __bf16* C) {
  __shared__ __attribute__((aligned(16))) __bf16 lA[128 * 64];
  __shared__ __attribute__((aligned(16))) __bf16 lB[128 * 64];
  const int t = threadIdx.x;
  const int m0 = blockIdx.y * 128, n0 = blockIdx.x * 128;
  const int lane = t & 63, wave = t >> 6;
  const int wm = (wave >> 1) * 64, wn = (wave & 1) * 64;
  const int l15 = lane & 15, l4 = lane >> 4;
  f32x4 acc[4][4];
#pragma unroll
  for (int i = 0; i < 4; i++)
#pragma unroll
    for (int j = 0; j < 4; j++) acc[i][j] = f32x4{0.f, 0.f, 0.f, 0.f};
  long long abase[4];
  int brow[4];
#pragma unroll
  for (int i = 0; i < 4; i++) {
    int slot = t + i * 256;
    int r = slot >> 3;
    int m = m0 + r;
    int b = m / 9216, hw = m % 9216;
    int h = hw / 96, w2 = hw % 96;
    abase[i] = ((long long)b * 9604 + h * 98 + w2) * 512;
    brow[i] = n0 + r;
  }
  for (int kt = 0; kt < 72; kt++) {  // K = 4608 = 72*64
    int dydx = kt >> 3;
    int c0k = (kt & 7) * 64;
    int dy = dydx / 3, dx = dydx - dy * 3;
    long long aoff = (long long)(dy * 98 + dx) * 512 + c0k;
    long long kb = (long long)kt * 64;
#pragma unroll
    for (int i = 0; i < 4; i++) {
      int slot = t + i * 256;
      int r = slot >> 3, c = slot & 7;
      int4 va = *(const int4*)(pin + abase[i] + aoff + c * 8);
      *(int4*)&lA[r * 64 + (((c + r) & 7) << 3)] = va;
      int4 vb = *(const int4*)(wr + (long long)brow[i] * 4608 + kb + c * 8);
      *(int4*)&lB[r * 64 + (((c + r) & 7) << 3)] = vb;
    }
    __syncthreads();
#pragma unroll
    for (int kk = 0; kk < 2; kk++) {
      bf8_t af[4], bfr[4];
      int cch = kk * 4 + l4;
#pragma unroll
      for (int mt = 0; mt < 4; mt++) {
        int r = wm + mt * 16 + l15;
        af[mt] = *(bf8_t*)&lA[r * 64 + (((cch + r) & 7) << 3)];
      }
#pragma unroll
      for (int nt = 0; nt < 4; nt++) {
        int r = wn + nt * 16 + l15;
        bfr[nt] = *(bf8_t*)&lB[r * 64 + (((cch + r) & 7) << 3)];
      }
#pragma unroll
      for (int mt = 0; mt < 4; mt++)
#pragma unroll
        for (int nt = 0; nt < 4; nt++)
          acc[mt][nt] = __builtin_amdgcn_mfma_f32_16x16x32_bf16(af[mt], bfr[nt], acc[mt][nt], 0, 0, 0);
    }
    __syncthreads();
  }
#pragma unroll
  for (int nt = 0; nt < 4; nt++) {
    int col = n0 + wn + nt * 16 + l15;
#pragma unroll
    for (int mt = 0; mt < 4; mt++) {
      int row0 = m0 + wm + mt * 16 + (l4 << 2);
#pragma unroll
      for (int r = 0; r < 4; r++) {
        int row = row0 + r;
        C[(long long)row * 512 + col] = (__bf16)acc[mt][nt][r];
      }
    }
  }
}

// ---------------------------------------------------------------- GroupNorm
__global__ __launch_bounds__(256) void gn_stats_k(const __bf16* z, float* stats) {
  int bg = blockIdx.x;
  int b = bg >> 5, g = bg & 31;
  int t = threadIdx.x;
  int cch = t & 1, sp0 = t >> 1;
  const __bf16* base = z + (long long)b * 9216 * 512 + g * 16 + cch * 8;
  float s = 0.f, ss = 0.f;
  for (int sp = sp0; sp < 9216; sp += 128) {
    I4B8 u;
    u.i = *(const int4*)(base + (long long)sp * 512);
#pragma unroll
    for (int j = 0; j < 8; j++) {
      float f = (float)u.b[j];
      s += f;
      ss += f * f;
    }
  }
#pragma unroll
  for (int o = 32; o; o >>= 1) {
    s += __shfl_xor(s, o);
    ss += __shfl_xor(ss, o);
  }
  __shared__ float red[8];
  int wave = t >> 6, lane = t & 63;
  if (lane == 0) {
    red[wave] = s;
    red[4 + wave] = ss;
  }
  __syncthreads();
  if (t == 0) {
    float S = red[0] + red[1] + red[2] + red[3];
    float SS = red[4] + red[5] + red[6] + red[7];
    const float inv = 1.f / 147456.f;
    float mean = S * inv;
    float var = SS * inv - mean * mean;
    stats[2 * bg] = mean;
    stats[2 * bg + 1] = rsqrtf(var + 1e-5f);
  }
}

// normalize + NHWC -> NCHW transpose write (fp32 out)
__global__ __launch_bounds__(256) void gn_write_k(const __bf16* z, const float* stats,
                                                 const float* gng, const float* gnb, float* out) {
  __shared__ __bf16 l[64 * 98];  // elem(w,c_local) at c_local*98 + w
  int c0 = blockIdx.x * 64, h = blockIdx.y, b = blockIdx.z;
  int t = threadIdx.x;
#pragma unroll
  for (int i = 0; i < 3; i++) {
    int slot = t + i * 256;
    int wl = slot >> 3, cch = slot & 7;
    I4B8 u;
    u.i = *(const int4*)(z + ((long long)(b * 9216 + h * 96 + wl)) * 512 + c0 + cch * 8);
#pragma unroll
    for (int j = 0; j < 8; j++) l[(cch * 8 + j) * 98 + wl] = u.b[j];
  }
  __syncthreads();
#pragma unroll
  for (int i = 0; i < 3; i++) {
    int slot = t + i * 256;
    int wch = slot % 12, cl = slot / 12;
    int c = c0 + cl;
    int g = c >> 4;
    float mean = stats[2 * (b * 32 + g)], rstd = stats[2 * (b * 32 + g) + 1];
    float sc = rstd * gng[c];
    float sh = gnb[c] - mean * sc;
    float4 o0, o1;
    const __bf16* src = &l[cl * 98 + wch * 8];
    o0.x = (float)src[0] * sc + sh; o0.y = (float)src[1] * sc + sh;
    o0.z = (float)src[2] * sc + sh; o0.w = (float)src[3] * sc + sh;
    o1.x = (float)src[4] * sc + sh; o1.y = (float)src[5] * sc + sh;
    o1.z = (float)src[6] * sc + sh; o1.w = (float)src[7] * sc + sh;
    float* dst = out + ((long long)((b * 512 + c) * 96 + h)) * 96 + wch * 8;
    *(float4*)dst = o0;
    *(float4*)(dst + 4) = o1;
  }
}

// ---------------------------------------------------------------- launch
extern "C" void kernel_launch(void* const* d_in, const int* in_sizes, int n_in,
                              void* d_out, int out_size, void* d_ws, size_t ws_size,
                              hipStream_t stream) {
  (void)in_sizes; (void)n_in; (void)out_size;
  const float* x = (const float*)d_in[0];
  const float* conv1w = (const float*)d_in[1];
  const float* conv1b = (const float*)d_in[2];
  const float* qw = (const float*)d_in[3];
  const float* qbias = (const float*)d_in[4];
  const float* kw = (const float*)d_in[5];
  const float* kbias = (const float*)d_in[6];
  const float* vw = (const float*)d_in[7];
  const float* vbias = (const float*)d_in[8];
  const float* gma = (const float*)d_in[9];
  const float* cow = (const float*)d_in[10];
  const float* gng = (const float*)d_in[11];
  const float* gnb = (const float*)d_in[12];
  float* out = (float*)d_out;

  if (ws_size < 136839680ULL) return;  // need ~137 MB scratch

  char* w = (char*)d_ws;
  __bf16* xt   = (__bf16*)(w);                 // 75,497,472 B (region R, reused later)
  __bf16* ya   = (__bf16*)(w + 75497472);      // 18,874,368
  __bf16* yb   = (__bf16*)(w + 94371840);      // 18,874,368
  __bf16* tmp1 = (__bf16*)(w + 113246208);     // 18,874,368
  __bf16* wr   = (__bf16*)(w + 132120576);     // 4,718,592
  float* stats = (float*)(w + 136839168);      // 512
  // aliases inside region R (xt dead after conv1):
  __bf16* qbuf  = (__bf16*)(w + 0);            // 2,359,296
  __bf16* kbuf  = (__bf16*)(w + 2359296);      // 2,359,296
  __bf16* vbuf  = (__bf16*)(w + 4718592);      // 18,874,368
  __bf16* attnb = (__bf16*)(w + 23592960);     // 7,077,888
  float* attnf  = (float*)(w + 30670848);      // 14,155,776
  __bf16* padb  = (__bf16*)(w + 0);            // 19,668,992 (after attention)
  __bf16* zb    = (__bf16*)(w + 19668992);     // 18,874,368
  // bf16 weight copies live inside tmp1's region (tmp1 unused until agg part1;
  // q/k/v weights re-cast each attention iteration since part1 clobbers them):
  __bf16* conv1wb = (__bf16*)(w + 113246208);  // 2,097,152
  __bf16* qwb     = (__bf16*)(w + 115343360);  // 65,536
  __bf16* kwb     = (__bf16*)(w + 115408896);  // 65,536
  __bf16* vwb     = (__bf16*)(w + 115474432);  // 524,288

  reorder_w_k<<<9216, 256, 0, stream>>>(cow, wr);
  transpose_x_k<<<dim3(32, 144, 2), 256, 0, stream>>>(x, xt);
  cast_f32_bf16_k<<<512, 256, 0, stream>>>(conv1w, conv1wb, 131072);

  {  // conv1 1x1: ya = xt @ conv1w^T + b
    GemmP p{};
    p.A = xt; p.sAr = 2048;
    p.B = conv1wb; p.sBr = 2048;
    p.C = ya; p.sCr = 512;
    p.M = 18432; p.N = 512; p.K = 2048; p.bdiv = 1; p.mode = 1; p.bias = conv1b;
    gemm_bt_k<0><<<dim3(4, 144, 1), 256, 0, stream>>>(p);
  }

  for (int it = 0; it < 2; it++) {
    __bf16* tin = it ? yb : ya;
    __bf16* tout = it ? ya : yb;
    cast_f32_bf16_k<<<16, 256, 0, stream>>>(qw, qwb, 4096);
    cast_f32_bf16_k<<<16, 256, 0, stream>>>(kw, kwb, 4096);
    cast_f32_bf16_k<<<128, 256, 0, stream>>>(vw, vwb, 32768);
    {  // q
      GemmP p{};
      p.A = tin; p.sAr = 512; p.B = qwb; p.sBr = 512; p.C = qbuf; p.sCr = 64;
      p.M = 18432; p.N = 64; p.K = 512; p.bdiv = 1; p.mode = 1; p.bias = qbias;
      gemm_bt_k<0><<<dim3(1, 144, 1), 256, 0, stream>>>(p);
    }
    {  // k
      GemmP p{};
      p.A = tin; p.sAr = 512; p.B = kwb; p.sBr = 512; p.C = kbuf; p.sCr = 64;
      p.M = 18432; p.N = 64; p.K = 512; p.bdiv = 1; p.mode = 1; p.bias = kbias;
      gemm_bt_k<0><<<dim3(1, 144, 1), 256, 0, stream>>>(p);
    }
    {  // v
      GemmP p{};
      p.A = tin; p.sAr = 512; p.B = vwb; p.sBr = 512; p.C = vbuf; p.sCr = 512;
      p.M = 18432; p.N = 512; p.K = 512; p.bdiv = 1; p.mode = 1; p.bias = vbias;
      gemm_bt_k<0><<<dim3(4, 144, 1), 256, 0, stream>>>(p);
    }
    cc_scores_k<<<dim3(192, 2), 384, 0, stream>>>(qbuf, kbuf, attnf);
    cc_softmax_k<<<4608, 256, 0, stream>>>(attnf, attnb);
    {  // agg part1: per (b,w): tmp1[h,c] = sum_i a_h[h,i] * v[b,i,w,c]
      GemmP p{};
      p.A = attnb; p.sAr = 96 * 192; p.sAb1 = (long long)96 * 96 * 192; p.sAb2 = 192;
      p.B = vbuf; p.sBr = (long long)96 * 512; p.sBb1 = (long long)9216 * 512; p.sBb2 = 512;
      p.C = tmp1; p.sCr = (long long)96 * 512; p.sCb1 = (long long)9216 * 512; p.sCb2 = 512;
      p.M = 96; p.N = 512; p.K = 96; p.bdiv = 96; p.mode = 0;
      gemm_bt_k<1><<<dim3(4, 1, 192), 256, 0, stream>>>(p);
    }
    {  // agg part2 + epilogue: per (b,h): out[w,c] = gamma*(tmp1 + sum_j a_w[w,j] v[b,h,j,c]) + tin
      GemmP p{};
      p.A = attnb + 96; p.sAr = 192; p.sAb1 = (long long)96 * 96 * 192; p.sAb2 = (long long)96 * 192;
      p.B = vbuf; p.sBr = 512; p.sBb1 = (long long)9216 * 512; p.sBb2 = (long long)96 * 512;
      p.C = tout; p.sCr = 512; p.sCb1 = (long long)9216 * 512; p.sCb2 = (long long)96 * 512;
      p.M = 96; p.N = 512; p.K = 96; p.bdiv = 96; p.mode = 2;
      p.tmp = tmp1; p.res = tin; p.gma = gma;
      gemm_bt_k<1><<<dim3(4, 1, 192), 256, 0, stream>>>(p);
    }
  }

  pad_k<<<4802, 256, 0, stream>>>(ya, padb);  // final attention output is in ya
  conv3_gemm_k<<<dim3(4, 144), 256, 0, stream>>>(padb, wr, zb);
  gn_stats_k<<<64, 256, 0, stream>>>(zb, stats);
  gn_write_k<<<dim3(8, 96, 2), 256, 0, stream>>>(zb, stats, gng, gnb, out);
}

// Round 3
// 760.239 us; speedup vs baseline: 1.1813x; 1.1813x over previous
//
#include <hip/hip_runtime.h>
#include <hip/hip_bf16.h>

// CCAttention pipeline on MI355X. fp32 in/out, bf16 MFMA internal, NHWC.
// B=2, CIN=2048, CINT=512, CQK=64, H=W=96, S=9216, NG=32.
// R3: XCD swizzle (m-major), global_load_lds async staging w/ pre-rotated
// global layouts (rotation key = row mod 8), fused qkv GEMM (N=640).

typedef __bf16 bf8_t __attribute__((ext_vector_type(8)));
typedef float f32x4 __attribute__((ext_vector_type(4)));

union I4B8 { int4 i; bf8_t b; };

typedef const __attribute__((address_space(1))) void as1_cvoid;
typedef __attribute__((address_space(3))) void as3_void;
__device__ __forceinline__ void gload16(const void* g, void* l) {
  __builtin_amdgcn_global_load_lds((as1_cvoid*)g, (as3_void*)l, 16, 0, 0);
}
__device__ __forceinline__ int rot8(int c, int key) { return (c + key) & 7; }

// ---------------------------------------------------------------- weight prep
// src f32 [N][K] row-major -> dst bf16 [N][K], 8-elem chunks rotated by n&7.
__global__ __launch_bounds__(256) void cast_rot_k(const float* s, __bf16* d, int K8, int total8) {
  int idx = blockIdx.x * 256 + threadIdx.x;
  if (idx >= total8) return;
  int c8 = idx % K8, n = idx / K8;
  int cch = c8 & 7;
  int pos = rot8(cch, n & 7);
  const float* sp = s + ((long long)n * K8 + c8) * 8;
  float4 a = *(const float4*)sp, b = *(const float4*)(sp + 4);
  I4B8 u;
  u.b[0] = (__bf16)a.x; u.b[1] = (__bf16)a.y; u.b[2] = (__bf16)a.z; u.b[3] = (__bf16)a.w;
  u.b[4] = (__bf16)b.x; u.b[5] = (__bf16)b.y; u.b[6] = (__bf16)b.z; u.b[7] = (__bf16)b.w;
  *(int4*)(d + ((long long)n * K8 + (c8 & ~7) + pos) * 8) = u.i;
}

// fused qkv weights: rows 0..63 q, 64..127 k, 128..639 v. K=512, rotated.
__global__ __launch_bounds__(256) void wqkv_rot_k(const float* qw, const float* kw, const float* vw, __bf16* d) {
  int idx = blockIdx.x * 256 + threadIdx.x;  // 640*64
  if (idx >= 640 * 64) return;
  int c8 = idx & 63, n = idx >> 6;
  const float* src = (n < 64) ? qw + (long long)n * 512
                   : (n < 128) ? kw + (long long)(n - 64) * 512
                               : vw + (long long)(n - 128) * 512;
  int cch = c8 & 7;
  int pos = rot8(cch, n & 7);
  const float* sp = src + c8 * 8;
  float4 a = *(const float4*)sp, b = *(const float4*)(sp + 4);
  I4B8 u;
  u.b[0] = (__bf16)a.x; u.b[1] = (__bf16)a.y; u.b[2] = (__bf16)a.z; u.b[3] = (__bf16)a.w;
  u.b[4] = (__bf16)b.x; u.b[5] = (__bf16)b.y; u.b[6] = (__bf16)b.z; u.b[7] = (__bf16)b.w;
  *(int4*)(d + ((long long)n * 64 + (c8 & ~7) + pos) * 8) = u.i;
}

__global__ __launch_bounds__(256) void fuse_bias_k(const float* qb, const float* kb, const float* vb, float* d) {
  int i = blockIdx.x * 256 + threadIdx.x;
  if (i >= 640) return;
  d[i] = (i < 64) ? qb[i] : (i < 128) ? kb[i - 64] : vb[i - 128];
}

// conv3 weights -> wr[o][dydx*512+c], rotated within 64-slices by o&7.
__global__ __launch_bounds__(256) void reorder_w_k(const float* w, __bf16* wr) {
  int idx = blockIdx.x * 256 + threadIdx.x;  // 512*9*64 chunk-threads
  if (idx >= 512 * 9 * 64) return;
  int ch8 = idx & 63;
  int r = idx >> 6;
  int dydx = r % 9, o = r / 9;
  int k = dydx * 512 + ch8 * 8;
  int cch = (k >> 3) & 7;
  int pos = rot8(cch, o & 7);
  const float* src = w + ((long long)o * 512 + ch8 * 8) * 9 + dydx;
  I4B8 u;
#pragma unroll
  for (int j = 0; j < 8; j++) u.b[j] = (__bf16)src[j * 9];
  *(int4*)(wr + (long long)o * 4608 + (k & ~63) + pos * 8) = u.i;
}

// x f32 NCHW -> xt bf16 NHWC, rotated by pixel&7.
__global__ __launch_bounds__(256) void transpose_x_k(const float* x, __bf16* xt) {
  __shared__ __bf16 l[64 * 66];
  int c0 = blockIdx.x * 64, s0 = blockIdx.y * 64, b = blockIdx.z;
  int t = threadIdx.x;
#pragma unroll
  for (int i = 0; i < 2; i++) {
    int slot = t + i * 256;
    int cl = slot >> 3, sch = slot & 7;
    const float* src = x + ((long long)(b * 2048 + c0 + cl)) * 9216 + s0 + sch * 8;
    float4 a = *(const float4*)src, bb = *(const float4*)(src + 4);
    __bf16* dst = &l[cl * 66 + sch * 8];
    dst[0] = (__bf16)a.x; dst[1] = (__bf16)a.y; dst[2] = (__bf16)a.z; dst[3] = (__bf16)a.w;
    dst[4] = (__bf16)bb.x; dst[5] = (__bf16)bb.y; dst[6] = (__bf16)bb.z; dst[7] = (__bf16)bb.w;
  }
  __syncthreads();
#pragma unroll
  for (int i = 0; i < 2; i++) {
    int slot = t + i * 256;
    int sl = slot >> 3, cch = slot & 7;
    I4B8 u;
#pragma unroll
    for (int j = 0; j < 8; j++) u.b[j] = l[(cch * 8 + j) * 66 + sl];
    *(int4*)(xt + ((long long)(b * 9216 + s0 + sl)) * 2048 + c0 + rot8(cch, sl & 7) * 8) = u.i;
  }
}

// zero-pad NHWC bf16 (de-rotates ya): pad[b][98][98][512]
__global__ __launch_bounds__(256) void pad_k(const __bf16* y, __bf16* pout) {
  long long idx = (long long)blockIdx.x * 256 + threadIdx.x;
  int cch = (int)(idx & 63);
  long long r = idx >> 6;
  int ww = (int)(r % 98);
  long long r2 = r / 98;
  int hh = (int)(r2 % 98);
  int b = (int)(r2 / 98);
  int4 v = make_int4(0, 0, 0, 0);
  if (hh >= 1 && hh <= 96 && ww >= 1 && ww <= 96) {
    long long pix = (long long)b * 9216 + (hh - 1) * 96 + (ww - 1);
    int slice = cch >> 3, sub = cch & 7;
    int phys = slice * 8 + rot8(sub, (int)(pix & 7));
    v = *(const int4*)(y + pix * 512 + phys * 8);
  }
  *(int4*)(pout + r * 512 + cch * 8) = v;
}

// ---------------------------------------------------------------- async GEMM
// C[M,N] = A[M,K]*B^T + bias. A,B pre-rotated global (key=row&7), staged via
// global_load_lds. M,N,K multiples of 128/128/64. XCD swizzle, m-major.
struct GemmAP {
  const __bf16 *A, *B;
  __bf16* C;
  const float* bias;
  long long sAr, sBr, sCr;
  int K, ntn;  // n-tile count
};

template <int CROT>
__global__ __launch_bounds__(256) void gemm_async_k(GemmAP p) {
  __shared__ __attribute__((aligned(16))) __bf16 lA[128 * 64];
  __shared__ __attribute__((aligned(16))) __bf16 lB[128 * 64];
  const int t = threadIdx.x;
  const int id = blockIdx.x;
  const int per8 = gridDim.x >> 3;
  const int lin = (id & 7) * per8 + (id >> 3);
  const int m0 = (lin / p.ntn) * 128, n0 = (lin % p.ntn) * 128;
  const int lane = t & 63, wave = t >> 6;
  const int wm = (wave >> 1) * 64, wn = (wave & 1) * 64;
  const int l15 = lane & 15, l4 = lane >> 4;
  const int srow = (lane >> 3), schunk = (lane & 7) * 8;
  f32x4 acc[4][4];
#pragma unroll
  for (int i = 0; i < 4; i++)
#pragma unroll
    for (int j = 0; j < 4; j++) acc[i][j] = f32x4{0.f, 0.f, 0.f, 0.f};

  for (int kb = 0; kb < p.K; kb += 64) {
    const int rb = wave * 32;
#pragma unroll
    for (int i = 0; i < 4; i++) {
      int row = rb + i * 8;
      gload16(p.A + (long long)(m0 + row + srow) * p.sAr + kb + schunk, &lA[row * 64]);
      gload16(p.B + (long long)(n0 + row + srow) * p.sBr + kb + schunk, &lB[row * 64]);
    }
    __syncthreads();
#pragma unroll
    for (int kk = 0; kk < 2; kk++) {
      bf8_t af[4], bfr[4];
      int cch = kk * 4 + l4;
#pragma unroll
      for (int mt = 0; mt < 4; mt++) {
        int r = wm + mt * 16 + l15;
        af[mt] = *(bf8_t*)&lA[r * 64 + (rot8(cch, r & 7) << 3)];
      }
#pragma unroll
      for (int nt = 0; nt < 4; nt++) {
        int r = wn + nt * 16 + l15;
        bfr[nt] = *(bf8_t*)&lB[r * 64 + (rot8(cch, r & 7) << 3)];
      }
#pragma unroll
      for (int mt = 0; mt < 4; mt++)
#pragma unroll
        for (int nt = 0; nt < 4; nt++)
          acc[mt][nt] = __builtin_amdgcn_mfma_f32_16x16x32_bf16(af[mt], bfr[nt], acc[mt][nt], 0, 0, 0);
    }
    __syncthreads();
  }
#pragma unroll
  for (int nt = 0; nt < 4; nt++) {
    int col = n0 + wn + nt * 16 + l15;
    float bv = p.bias[col];
#pragma unroll
    for (int mt = 0; mt < 4; mt++) {
      int row0 = m0 + wm + mt * 16 + (l4 << 2);
#pragma unroll
      for (int r = 0; r < 4; r++) {
        int row = row0 + r;
        int pc = CROT ? (col & ~63) + (rot8((col >> 3) & 7, row & 7) << 3) + (col & 7) : col;
        p.C[(long long)row * p.sCr + pc] = (__bf16)(acc[mt][nt][r] + bv);
      }
    }
  }
}

// ---------------------------------------------------------------- agg GEMM
// Small batched GEMM for attention aggregation. A staged via VGPR (clamped),
// B transposed-in-LDS from K x N source. mode 0: plain C; mode 2:
// C = gamma*(tmp+acc)+res (res/C rotated when CROT=1, tmp logical).
struct GemmP {
  const __bf16 *A, *B;
  __bf16* C;
  long long sAr, sAb1, sAb2;
  long long sBr, sBb1, sBb2;
  long long sCr, sCb1, sCb2;
  int M, N, K, bdiv, mode;
  const __bf16 *tmp, *res;
  const float* gma;
};

template <int CROT>
__global__ __launch_bounds__(256) void gemm_bt_k(GemmP p) {
  __shared__ __attribute__((aligned(16))) __bf16 lA[128 * 64];
  __shared__ __attribute__((aligned(16))) __bf16 lB[128 * 64];
  const int t = threadIdx.x;
  const int z = blockIdx.z;
  const int z1 = z / p.bdiv, z2 = z % p.bdiv;
  const __bf16* A = p.A + (long long)z1 * p.sAb1 + (long long)z2 * p.sAb2;
  const __bf16* B = p.B + (long long)z1 * p.sBb1 + (long long)z2 * p.sBb2;
  const int m0 = blockIdx.y * 128, n0 = blockIdx.x * 128;
  const int lane = t & 63, wave = t >> 6;
  const int wm = (wave >> 1) * 64, wn = (wave & 1) * 64;
  const int l15 = lane & 15, l4 = lane >> 4;
  f32x4 acc[4][4];
#pragma unroll
  for (int i = 0; i < 4; i++)
#pragma unroll
    for (int j = 0; j < 4; j++) acc[i][j] = f32x4{0.f, 0.f, 0.f, 0.f};

  int arow[4];
#pragma unroll
  for (int i = 0; i < 4; i++) {
    int slot = t + i * 256;
    arow[i] = min(m0 + (slot >> 3), p.M - 1);
  }
  for (int kb = 0; kb < p.K; kb += 64) {
#pragma unroll
    for (int i = 0; i < 4; i++) {
      int slot = t + i * 256;
      int r = slot >> 3, c = slot & 7;
      int gk = kb + c * 8;
      int4 v = make_int4(0, 0, 0, 0);
      if (gk < p.K) v = *(const int4*)(A + (long long)arow[i] * p.sAr + gk);
      *(int4*)&lA[r * 64 + (rot8(c, r & 7) << 3)] = v;
    }
#pragma unroll
    for (int i = 0; i < 4; i++) {
      int slot = t + i * 256;
      int kl = slot & 63, cch = slot >> 6;
      int gk = kb + kl;
      I4B8 u;
      u.i = make_int4(0, 0, 0, 0);
      if (gk < p.K) u.i = *(const int4*)(B + (long long)gk * p.sBr + n0 + cch * 8);
#pragma unroll
      for (int j = 0; j < 8; j++) {
        int n = cch * 8 + j;
        lB[n * 64 + (rot8(kl >> 3, n & 7) << 3) + (kl & 7)] = u.b[j];
      }
    }
    __syncthreads();
#pragma unroll
    for (int kk = 0; kk < 2; kk++) {
      bf8_t af[4], bfr[4];
      int cch = kk * 4 + l4;
#pragma unroll
      for (int mt = 0; mt < 4; mt++) {
        int r = wm + mt * 16 + l15;
        af[mt] = *(bf8_t*)&lA[r * 64 + (rot8(cch, r & 7) << 3)];
      }
#pragma unroll
      for (int nt = 0; nt < 4; nt++) {
        int r = wn + nt * 16 + l15;
        bfr[nt] = *(bf8_t*)&lB[r * 64 + (rot8(cch, r & 7) << 3)];
      }
#pragma unroll
      for (int mt = 0; mt < 4; mt++)
#pragma unroll
        for (int nt = 0; nt < 4; nt++)
          acc[mt][nt] = __builtin_amdgcn_mfma_f32_16x16x32_bf16(af[mt], bfr[nt], acc[mt][nt], 0, 0, 0);
    }
    __syncthreads();
  }
  long long coff = (long long)z1 * p.sCb1 + (long long)z2 * p.sCb2;
  float g = (p.mode == 2) ? *p.gma : 0.f;
#pragma unroll
  for (int nt = 0; nt < 4; nt++) {
    int col = n0 + wn + nt * 16 + l15;
    if (col >= p.N) continue;
#pragma unroll
    for (int mt = 0; mt < 4; mt++) {
      int row0 = m0 + wm + mt * 16 + (l4 << 2);
#pragma unroll
      for (int r = 0; r < 4; r++) {
        int row = row0 + r;
        if (row >= p.M) continue;
        long long offL = coff + (long long)row * p.sCr + col;
        long long offP = offL;
        if (CROT)
          offP = coff + (long long)row * p.sCr +
                 (col & ~63) + (rot8((col >> 3) & 7, row & 7) << 3) + (col & 7);
        float v = acc[mt][nt][r];
        if (p.mode == 2)
          v = g * ((float)p.tmp[offL] + v) + (float)p.res[offP];
        p.C[offP] = (__bf16)v;
      }
    }
  }
}

// ---------------------------------------------------------------- scores
// qkv unrotated: q cols 0..63, k cols 64..127, row stride 640.
__global__ __launch_bounds__(384) void cc_scores_k(const __bf16* qkv, float* attnf) {
  __shared__ __attribute__((aligned(16))) __bf16 Qs[96 * 64];
  __shared__ __attribute__((aligned(16))) __bf16 Ks[96 * 64];
  int bfi = blockIdx.x;
  int b = bfi / 96, f = bfi % 96;
  int mode = blockIdx.y;
  long long base = (mode == 0) ? ((long long)(b * 9216 + f)) * 640 : ((long long)(b * 9216 + f * 96)) * 640;
  long long rstr = (mode == 0) ? 96 * 640 : 640;
  int t = threadIdx.x;
#pragma unroll
  for (int i = 0; i < 2; i++) {
    int slot = t + i * 384;
    int r = slot >> 3, c = slot & 7;
    int sw = rot8(c, r & 7) << 3;
    *(int4*)&Qs[r * 64 + sw] = *(const int4*)(qkv + base + (long long)r * rstr + c * 8);
    *(int4*)&Ks[r * 64 + sw] = *(const int4*)(qkv + base + (long long)r * rstr + 64 + c * 8);
  }
  __syncthreads();
  int lane = t & 63, wave = t >> 6;
  int l15 = lane & 15, l4 = lane >> 4;
  f32x4 acc[6];
#pragma unroll
  for (int i = 0; i < 6; i++) acc[i] = f32x4{0.f, 0.f, 0.f, 0.f};
#pragma unroll
  for (int kk = 0; kk < 2; kk++) {
    int ar = wave * 16 + l15;
    int cch = kk * 4 + l4;
    bf8_t af = *(bf8_t*)&Qs[ar * 64 + (rot8(cch, ar & 7) << 3)];
#pragma unroll
    for (int nt = 0; nt < 6; nt++) {
      int br = nt * 16 + l15;
      bf8_t bfr = *(bf8_t*)&Ks[br * 64 + (rot8(cch, br & 7) << 3)];
      acc[nt] = __builtin_amdgcn_mfma_f32_16x16x32_bf16(af, bfr, acc[nt], 0, 0, 0);
    }
  }
#pragma unroll
  for (int nt = 0; nt < 6; nt++) {
#pragma unroll
    for (int r = 0; r < 4; r++) {
      int m = wave * 16 + (l4 << 2) + r;
      int n = nt * 16 + l15;
      float v = acc[nt][r];
      long long off;
      if (mode == 0) {
        if (n == m) v = -__builtin_inff();
        off = ((long long)((b * 96 + m) * 96 + f)) * 192 + n;
      } else {
        off = ((long long)((b * 96 + f) * 96 + m)) * 192 + 96 + n;
      }
      attnf[off] = v;
    }
  }
}

__global__ __launch_bounds__(256) void cc_softmax_k(const float* attnf, __bf16* attnb) {
  int wave = threadIdx.x >> 6, lane = threadIdx.x & 63;
  long long row = (long long)blockIdx.x * 4 + wave;
  const float* src = attnf + row * 192;
  float e0 = src[lane], e1 = src[lane + 64], e2 = src[lane + 128];
  float m = fmaxf(e0, fmaxf(e1, e2));
#pragma unroll
  for (int o = 32; o; o >>= 1) m = fmaxf(m, __shfl_xor(m, o));
  e0 = __expf(e0 - m);
  e1 = __expf(e1 - m);
  e2 = __expf(e2 - m);
  float s = e0 + e1 + e2;
#pragma unroll
  for (int o = 32; o; o >>= 1) s += __shfl_xor(s, o);
  float inv = 1.f / s;
  __bf16* dst = attnb + row * 192;
  dst[lane] = (__bf16)(e0 * inv);
  dst[lane + 64] = (__bf16)(e1 * inv);
  dst[lane + 128] = (__bf16)(e2 * inv);
}

// ---------------------------------------------------------------- conv3x3
// A (padb) unrotated via VGPR staging; B (wrot) rotated via global_load_lds.
__global__ __launch_bounds__(256) void conv3_gemm_k(const __bf16* pin, const __bf16* wr, __bf16* C) {
  __shared__ __attribute__((aligned(16))) __bf16 lA[128 * 64];
  __shared__ __attribute__((aligned(16))) __bf16 lB[128 * 64];
  const int t = threadIdx.x;
  const int id = blockIdx.x;
  const int per8 = gridDim.x >> 3;                 // 72
  const int lin = (id & 7) * per8 + (id >> 3);
  const int m0 = (lin >> 2) * 128, n0 = (lin & 3) * 128;   // m-major, ntn=4
  const int lane = t & 63, wave = t >> 6;
  const int wm = (wave >> 1) * 64, wn = (wave & 1) * 64;
  const int l15 = lane & 15, l4 = lane >> 4;
  const int srow = lane >> 3, schunk = (lane & 7) * 8;
  f32x4 acc[4][4];
#pragma unroll
  for (int i = 0; i < 4; i++)
#pragma unroll
    for (int j = 0; j < 4; j++) acc[i][j] = f32x4{0.f, 0.f, 0.f, 0.f};
  long long abase[4];
#pragma unroll
  for (int i = 0; i < 4; i++) {
    int slot = t + i * 256;
    int r = slot >> 3;
    int m = m0 + r;
    int b = m / 9216, hw = m % 9216;
    int h = hw / 96, w2 = hw % 96;
    abase[i] = ((long long)b * 9604 + h * 98 + w2) * 512;
  }
  for (int kt = 0; kt < 72; kt++) {  // K = 4608 = 72*64
    int dydx = kt >> 3;
    int c0k = (kt & 7) * 64;
    int dy = dydx / 3, dx = dydx - dy * 3;
    long long aoff = (long long)(dy * 98 + dx) * 512 + c0k;
    long long kb = (long long)kt * 64;
    {
      int rb = wave * 32;
#pragma unroll
      for (int i = 0; i < 4; i++) {
        int row = rb + i * 8;
        gload16(wr + (long long)(n0 + row + srow) * 4608 + kb + schunk, &lB[row * 64]);
      }
    }
#pragma unroll
    for (int i = 0; i < 4; i++) {
      int slot = t + i * 256;
      int r = slot >> 3, c = slot & 7;
      int4 va = *(const int4*)(pin + abase[i] + aoff + c * 8);
      *(int4*)&lA[r * 64 + (rot8(c, r & 7) << 3)] = va;
    }
    __syncthreads();
#pragma unroll
    for (int kk = 0; kk < 2; kk++) {
      bf8_t af[4], bfr[4];
      int cch = kk * 4 + l4;
#pragma unroll
      for (int mt = 0; mt < 4; mt++) {
        int r = wm + mt * 16 + l15;
        af[mt] = *(bf8_t*)&lA[r * 64 + (rot8(cch, r & 7) << 3)];
      }
#pragma unroll
      for (int nt = 0; nt < 4; nt++) {
        int r = wn + nt * 16 + l15;
        bfr[nt] = *(bf8_t*)&lB[r * 64 + (rot8(cch, r & 7) << 3)];
      }
#pragma unroll
      for (int mt = 0; mt < 4; mt++)
#pragma unroll
        for (int nt = 0; nt < 4; nt++)
          acc[mt][nt] = __builtin_amdgcn_mfma_f32_16x16x32_bf16(af[mt], bfr[nt], acc[mt][nt], 0, 0, 0);
    }
    __syncthreads();
  }
#pragma unroll
  for (int nt = 0; nt < 4; nt++) {
    int col = n0 + wn + nt * 16 + l15;
#pragma unroll
    for (int mt = 0; mt < 4; mt++) {
      int row0 = m0 + wm + mt * 16 + (l4 << 2);
#pragma unroll
      for (int r = 0; r < 4; r++) {
        int row = row0 + r;
        C[(long long)row * 512 + col] = (__bf16)acc[mt][nt][r];
      }
    }
  }
}

// ---------------------------------------------------------------- GroupNorm
__global__ __launch_bounds__(256) void gn_stats_k(const __bf16* z, float* stats) {
  int bg = blockIdx.x;
  int b = bg >> 5, g = bg & 31;
  int t = threadIdx.x;
  int cch = t & 1, sp0 = t >> 1;
  const __bf16* base = z + (long long)b * 9216 * 512 + g * 16 + cch * 8;
  float s = 0.f, ss = 0.f;
  for (int sp = sp0; sp < 9216; sp += 128) {
    I4B8 u;
    u.i = *(const int4*)(base + (long long)sp * 512);
#pragma unroll
    for (int j = 0; j < 8; j++) {
      float f = (float)u.b[j];
      s += f;
      ss += f * f;
    }
  }
#pragma unroll
  for (int o = 32; o; o >>= 1) {
    s += __shfl_xor(s, o);
    ss += __shfl_xor(ss, o);
  }
  __shared__ float red[8];
  int wave = t >> 6, lane = t & 63;
  if (lane == 0) {
    red[wave] = s;
    red[4 + wave] = ss;
  }
  __syncthreads();
  if (t == 0) {
    float S = red[0] + red[1] + red[2] + red[3];
    float SS = red[4] + red[5] + red[6] + red[7];
    const float inv = 1.f / 147456.f;
    float mean = S * inv;
    float var = SS * inv - mean * mean;
    stats[2 * bg] = mean;
    stats[2 * bg + 1] = rsqrtf(var + 1e-5f);
  }
}

__global__ __launch_bounds__(256) void gn_write_k(const __bf16* z, const float* stats,
                                                 const float* gng, const float* gnb, float* out) {
  __shared__ __bf16 l[64 * 98];
  int c0 = blockIdx.x * 64, h = blockIdx.y, b = blockIdx.z;
  int t = threadIdx.x;
#pragma unroll
  for (int i = 0; i < 3; i++) {
    int slot = t + i * 256;
    int wl = slot >> 3, cch = slot & 7;
    I4B8 u;
    u.i = *(const int4*)(z + ((long long)(b * 9216 + h * 96 + wl)) * 512 + c0 + cch * 8);
#pragma unroll
    for (int j = 0; j < 8; j++) l[(cch * 8 + j) * 98 + wl] = u.b[j];
  }
  __syncthreads();
#pragma unroll
  for (int i = 0; i < 3; i++) {
    int slot = t + i * 256;
    int wch = slot % 12, cl = slot / 12;
    int c = c0 + cl;
    int g = c >> 4;
    float mean = stats[2 * (b * 32 + g)], rstd = stats[2 * (b * 32 + g) + 1];
    float sc = rstd * gng[c];
    float sh = gnb[c] - mean * sc;
    float4 o0, o1;
    const __bf16* src = &l[cl * 98 + wch * 8];
    o0.x = (float)src[0] * sc + sh; o0.y = (float)src[1] * sc + sh;
    o0.z = (float)src[2] * sc + sh; o0.w = (float)src[3] * sc + sh;
    o1.x = (float)src[4] * sc + sh; o1.y = (float)src[5] * sc + sh;
    o1.z = (float)src[6] * sc + sh; o1.w = (float)src[7] * sc + sh;
    float* dst = out + ((long long)((b * 512 + c) * 96 + h)) * 96 + wch * 8;
    *(float4*)dst = o0;
    *(float4*)(dst + 4) = o1;
  }
}

// ---------------------------------------------------------------- launch
extern "C" void kernel_launch(void* const* d_in, const int* in_sizes, int n_in,
                              void* d_out, int out_size, void* d_ws, size_t ws_size,
                              hipStream_t stream) {
  (void)in_sizes; (void)n_in; (void)out_size;
  const float* x = (const float*)d_in[0];
  const float* conv1w = (const float*)d_in[1];
  const float* conv1b = (const float*)d_in[2];
  const float* qw = (const float*)d_in[3];
  const float* qbias = (const float*)d_in[4];
  const float* kw = (const float*)d_in[5];
  const float* kbias = (const float*)d_in[6];
  const float* vw = (const float*)d_in[7];
  const float* vbias = (const float*)d_in[8];
  const float* gma = (const float*)d_in[9];
  const float* cow = (const float*)d_in[10];
  const float* gng = (const float*)d_in[11];
  const float* gnb = (const float*)d_in[12];
  float* out = (float*)d_out;

  if (ws_size < 134876160ULL) return;

  char* w = (char*)d_ws;
  // region0 [0, 75.5 MB): xt during conv1; then qkv+attnb; then padb+zb+wrot
  __bf16* xt    = (__bf16*)(w);                 // 75,497,472
  __bf16* qkv   = (__bf16*)(w);                 // 23,592,960
  __bf16* attnb = (__bf16*)(w + 23592960);      // 7,077,888
  __bf16* padb  = (__bf16*)(w);                 // 19,668,992
  __bf16* zb    = (__bf16*)(w + 19668992);      // 18,874,368
  __bf16* wrot  = (__bf16*)(w + 38543360);      // 4,718,592
  __bf16* ya    = (__bf16*)(w + 75497472);      // 18,874,368
  __bf16* yb    = (__bf16*)(w + 94371840);      // 18,874,368
  __bf16* tmp1  = (__bf16*)(w + 113246208);     // 18,874,368 (attnf aliases)
  float* attnf  = (float*)(w + 113246208);      // 14,155,776
  __bf16* c1wb  = (__bf16*)(w + 132120576);     // 2,097,152
  __bf16* wqkvb = (__bf16*)(w + 134217728);     // 655,360
  float* qkvbias = (float*)(w + 134873088);     // 2,560
  float* stats   = (float*)(w + 134875648);     // 512

  cast_rot_k<<<512, 256, 0, stream>>>(conv1w, c1wb, 256, 131072);
  wqkv_rot_k<<<160, 256, 0, stream>>>(qw, kw, vw, wqkvb);
  fuse_bias_k<<<3, 256, 0, stream>>>(qbias, kbias, vbias, qkvbias);
  transpose_x_k<<<dim3(32, 144, 2), 256, 0, stream>>>(x, xt);

  {  // conv1: ya = xt @ c1wb^T + b (rotated out)
    GemmAP p{};
    p.A = xt; p.B = c1wb; p.C = ya; p.bias = conv1b;
    p.sAr = 2048; p.sBr = 2048; p.sCr = 512;
    p.K = 2048; p.ntn = 4;
    gemm_async_k<1><<<576, 256, 0, stream>>>(p);
  }

  for (int it = 0; it < 2; it++) {
    __bf16* tin = it ? yb : ya;
    __bf16* tout = it ? ya : yb;
    {  // fused qkv projection
      GemmAP p{};
      p.A = tin; p.B = wqkvb; p.C = qkv; p.bias = qkvbias;
      p.sAr = 512; p.sBr = 512; p.sCr = 640;
      p.K = 512; p.ntn = 5;
      gemm_async_k<0><<<720, 256, 0, stream>>>(p);
    }
    cc_scores_k<<<dim3(192, 2), 384, 0, stream>>>(qkv, attnf);
    cc_softmax_k<<<4608, 256, 0, stream>>>(attnf, attnb);
    {  // agg1: per (b,w): tmp1[h,c] = sum_i a_h[h,i] * v[b,i,w,c]
      GemmP p{};
      p.A = attnb; p.sAr = 96 * 192; p.sAb1 = (long long)96 * 96 * 192; p.sAb2 = 192;
      p.B = qkv + 128; p.sBr = (long long)96 * 640; p.sBb1 = (long long)9216 * 640; p.sBb2 = 640;
      p.C = tmp1; p.sCr = (long long)96 * 512; p.sCb1 = (long long)9216 * 512; p.sCb2 = 512;
      p.M = 96; p.N = 512; p.K = 96; p.bdiv = 96; p.mode = 0;
      gemm_bt_k<0><<<dim3(4, 1, 192), 256, 0, stream>>>(p);
    }
    {  // agg2 + epilogue (rotated out/res)
      GemmP p{};
      p.A = attnb + 96; p.sAr = 192; p.sAb1 = (long long)96 * 96 * 192; p.sAb2 = (long long)96 * 192;
      p.B = qkv + 128; p.sBr = 640; p.sBb1 = (long long)9216 * 640; p.sBb2 = (long long)96 * 640;
      p.C = tout; p.sCr = 512; p.sCb1 = (long long)9216 * 512; p.sCb2 = (long long)96 * 512;
      p.M = 96; p.N = 512; p.K = 96; p.bdiv = 96; p.mode = 2;
      p.tmp = tmp1; p.res = tin; p.gma = gma;
      gemm_bt_k<1><<<dim3(4, 1, 192), 256, 0, stream>>>(p);
    }
  }

  reorder_w_k<<<1152, 256, 0, stream>>>(cow, wrot);
  pad_k<<<4802, 256, 0, stream>>>(ya, padb);  // final attention output is in ya
  conv3_gemm_k<<<576, 256, 0, stream>>>(padb, wrot, zb);
  gn_stats_k<<<64, 256, 0, stream>>>(zb, stats);
  gn_write_k<<<dim3(8, 96, 2), 256, 0, stream>>>(zb, stats, gng, gnb, out);
}

// Round 4
// 693.126 us; speedup vs baseline: 1.2956x; 1.0968x over previous
//
#include <hip/hip_runtime.h>
#include <hip/hip_bf16.h>

// CCAttention pipeline on MI355X. fp32 in/out, bf16 MFMA internal, NHWC.
// B=2, CIN=2048, CINT=512, CQK=64, H=W=96, S=9216, NG=32.
// R4: conv3 A-operand staged via global_load_lds (rotation keyed by padded-w
// mod 8, baked into pad_k). Rest identical to R3.

typedef __bf16 bf8_t __attribute__((ext_vector_type(8)));
typedef float f32x4 __attribute__((ext_vector_type(4)));

union I4B8 { int4 i; bf8_t b; };

typedef const __attribute__((address_space(1))) void as1_cvoid;
typedef __attribute__((address_space(3))) void as3_void;
__device__ __forceinline__ void gload16(const void* g, void* l) {
  __builtin_amdgcn_global_load_lds((as1_cvoid*)g, (as3_void*)l, 16, 0, 0);
}
__device__ __forceinline__ int rot8(int c, int key) { return (c + key) & 7; }

// ---------------------------------------------------------------- weight prep
__global__ __launch_bounds__(256) void cast_rot_k(const float* s, __bf16* d, int K8, int total8) {
  int idx = blockIdx.x * 256 + threadIdx.x;
  if (idx >= total8) return;
  int c8 = idx % K8, n = idx / K8;
  int cch = c8 & 7;
  int pos = rot8(cch, n & 7);
  const float* sp = s + ((long long)n * K8 + c8) * 8;
  float4 a = *(const float4*)sp, b = *(const float4*)(sp + 4);
  I4B8 u;
  u.b[0] = (__bf16)a.x; u.b[1] = (__bf16)a.y; u.b[2] = (__bf16)a.z; u.b[3] = (__bf16)a.w;
  u.b[4] = (__bf16)b.x; u.b[5] = (__bf16)b.y; u.b[6] = (__bf16)b.z; u.b[7] = (__bf16)b.w;
  *(int4*)(d + ((long long)n * K8 + (c8 & ~7) + pos) * 8) = u.i;
}

__global__ __launch_bounds__(256) void wqkv_rot_k(const float* qw, const float* kw, const float* vw, __bf16* d) {
  int idx = blockIdx.x * 256 + threadIdx.x;  // 640*64
  if (idx >= 640 * 64) return;
  int c8 = idx & 63, n = idx >> 6;
  const float* src = (n < 64) ? qw + (long long)n * 512
                   : (n < 128) ? kw + (long long)(n - 64) * 512
                               : vw + (long long)(n - 128) * 512;
  int cch = c8 & 7;
  int pos = rot8(cch, n & 7);
  const float* sp = src + c8 * 8;
  float4 a = *(const float4*)sp, b = *(const float4*)(sp + 4);
  I4B8 u;
  u.b[0] = (__bf16)a.x; u.b[1] = (__bf16)a.y; u.b[2] = (__bf16)a.z; u.b[3] = (__bf16)a.w;
  u.b[4] = (__bf16)b.x; u.b[5] = (__bf16)b.y; u.b[6] = (__bf16)b.z; u.b[7] = (__bf16)b.w;
  *(int4*)(d + ((long long)n * 64 + (c8 & ~7) + pos) * 8) = u.i;
}

__global__ __launch_bounds__(256) void fuse_bias_k(const float* qb, const float* kb, const float* vb, float* d) {
  int i = blockIdx.x * 256 + threadIdx.x;
  if (i >= 640) return;
  d[i] = (i < 64) ? qb[i] : (i < 128) ? kb[i - 64] : vb[i - 128];
}

// conv3 weights -> wr[o][dydx*512+c], rotated within 64-slices by o&7.
__global__ __launch_bounds__(256) void reorder_w_k(const float* w, __bf16* wr) {
  int idx = blockIdx.x * 256 + threadIdx.x;  // 512*9*64 chunk-threads
  if (idx >= 512 * 9 * 64) return;
  int ch8 = idx & 63;
  int r = idx >> 6;
  int dydx = r % 9, o = r / 9;
  int k = dydx * 512 + ch8 * 8;
  int cch = (k >> 3) & 7;
  int pos = rot8(cch, o & 7);
  const float* src = w + ((long long)o * 512 + ch8 * 8) * 9 + dydx;
  I4B8 u;
#pragma unroll
  for (int j = 0; j < 8; j++) u.b[j] = (__bf16)src[j * 9];
  *(int4*)(wr + (long long)o * 4608 + (k & ~63) + pos * 8) = u.i;
}

// x f32 NCHW -> xt bf16 NHWC, rotated by pixel&7.
__global__ __launch_bounds__(256) void transpose_x_k(const float* x, __bf16* xt) {
  __shared__ __bf16 l[64 * 66];
  int c0 = blockIdx.x * 64, s0 = blockIdx.y * 64, b = blockIdx.z;
  int t = threadIdx.x;
#pragma unroll
  for (int i = 0; i < 2; i++) {
    int slot = t + i * 256;
    int cl = slot >> 3, sch = slot & 7;
    const float* src = x + ((long long)(b * 2048 + c0 + cl)) * 9216 + s0 + sch * 8;
    float4 a = *(const float4*)src, bb = *(const float4*)(src + 4);
    __bf16* dst = &l[cl * 66 + sch * 8];
    dst[0] = (__bf16)a.x; dst[1] = (__bf16)a.y; dst[2] = (__bf16)a.z; dst[3] = (__bf16)a.w;
    dst[4] = (__bf16)bb.x; dst[5] = (__bf16)bb.y; dst[6] = (__bf16)bb.z; dst[7] = (__bf16)bb.w;
  }
  __syncthreads();
#pragma unroll
  for (int i = 0; i < 2; i++) {
    int slot = t + i * 256;
    int sl = slot >> 3, cch = slot & 7;
    I4B8 u;
#pragma unroll
    for (int j = 0; j < 8; j++) u.b[j] = l[(cch * 8 + j) * 66 + sl];
    *(int4*)(xt + ((long long)(b * 9216 + s0 + sl)) * 2048 + c0 + rot8(cch, sl & 7) * 8) = u.i;
  }
}

// zero-pad NHWC bf16: de-rotate ya (key pix&7), re-rotate by padded-w (ww&7).
__global__ __launch_bounds__(256) void pad_k(const __bf16* y, __bf16* pout) {
  long long idx = (long long)blockIdx.x * 256 + threadIdx.x;
  int cch = (int)(idx & 63);
  long long r = idx >> 6;
  int ww = (int)(r % 98);
  long long r2 = r / 98;
  int hh = (int)(r2 % 98);
  int b = (int)(r2 / 98);
  int slice = cch >> 3, sub = cch & 7;
  int4 v = make_int4(0, 0, 0, 0);
  if (hh >= 1 && hh <= 96 && ww >= 1 && ww <= 96) {
    long long pix = (long long)b * 9216 + (hh - 1) * 96 + (ww - 1);
    v = *(const int4*)(y + pix * 512 + (slice * 8 + rot8(sub, (int)(pix & 7))) * 8);
  }
  *(int4*)(pout + r * 512 + (slice * 8 + rot8(sub, ww & 7)) * 8) = v;
}

// ---------------------------------------------------------------- async GEMM
struct GemmAP {
  const __bf16 *A, *B;
  __bf16* C;
  const float* bias;
  long long sAr, sBr, sCr;
  int K, ntn;
};

template <int CROT>
__global__ __launch_bounds__(256) void gemm_async_k(GemmAP p) {
  __shared__ __attribute__((aligned(16))) __bf16 lA[128 * 64];
  __shared__ __attribute__((aligned(16))) __bf16 lB[128 * 64];
  const int t = threadIdx.x;
  const int id = blockIdx.x;
  const int per8 = gridDim.x >> 3;
  const int lin = (id & 7) * per8 + (id >> 3);
  const int m0 = (lin / p.ntn) * 128, n0 = (lin % p.ntn) * 128;
  const int lane = t & 63, wave = t >> 6;
  const int wm = (wave >> 1) * 64, wn = (wave & 1) * 64;
  const int l15 = lane & 15, l4 = lane >> 4;
  const int srow = (lane >> 3), schunk = (lane & 7) * 8;
  f32x4 acc[4][4];
#pragma unroll
  for (int i = 0; i < 4; i++)
#pragma unroll
    for (int j = 0; j < 4; j++) acc[i][j] = f32x4{0.f, 0.f, 0.f, 0.f};

  for (int kb = 0; kb < p.K; kb += 64) {
    const int rb = wave * 32;
#pragma unroll
    for (int i = 0; i < 4; i++) {
      int row = rb + i * 8;
      gload16(p.A + (long long)(m0 + row + srow) * p.sAr + kb + schunk, &lA[row * 64]);
      gload16(p.B + (long long)(n0 + row + srow) * p.sBr + kb + schunk, &lB[row * 64]);
    }
    __syncthreads();
#pragma unroll
    for (int kk = 0; kk < 2; kk++) {
      bf8_t af[4], bfr[4];
      int cch = kk * 4 + l4;
#pragma unroll
      for (int mt = 0; mt < 4; mt++) {
        int r = wm + mt * 16 + l15;
        af[mt] = *(bf8_t*)&lA[r * 64 + (rot8(cch, r & 7) << 3)];
      }
#pragma unroll
      for (int nt = 0; nt < 4; nt++) {
        int r = wn + nt * 16 + l15;
        bfr[nt] = *(bf8_t*)&lB[r * 64 + (rot8(cch, r & 7) << 3)];
      }
#pragma unroll
      for (int mt = 0; mt < 4; mt++)
#pragma unroll
        for (int nt = 0; nt < 4; nt++)
          acc[mt][nt] = __builtin_amdgcn_mfma_f32_16x16x32_bf16(af[mt], bfr[nt], acc[mt][nt], 0, 0, 0);
    }
    __syncthreads();
  }
#pragma unroll
  for (int nt = 0; nt < 4; nt++) {
    int col = n0 + wn + nt * 16 + l15;
    float bv = p.bias[col];
#pragma unroll
    for (int mt = 0; mt < 4; mt++) {
      int row0 = m0 + wm + mt * 16 + (l4 << 2);
#pragma unroll
      for (int r = 0; r < 4; r++) {
        int row = row0 + r;
        int pc = CROT ? (col & ~63) + (rot8((col >> 3) & 7, row & 7) << 3) + (col & 7) : col;
        p.C[(long long)row * p.sCr + pc] = (__bf16)(acc[mt][nt][r] + bv);
      }
    }
  }
}

// ---------------------------------------------------------------- agg GEMM
struct GemmP {
  const __bf16 *A, *B;
  __bf16* C;
  long long sAr, sAb1, sAb2;
  long long sBr, sBb1, sBb2;
  long long sCr, sCb1, sCb2;
  int M, N, K, bdiv, mode;
  const __bf16 *tmp, *res;
  const float* gma;
};

template <int CROT>
__global__ __launch_bounds__(256) void gemm_bt_k(GemmP p) {
  __shared__ __attribute__((aligned(16))) __bf16 lA[128 * 64];
  __shared__ __attribute__((aligned(16))) __bf16 lB[128 * 64];
  const int t = threadIdx.x;
  const int z = blockIdx.z;
  const int z1 = z / p.bdiv, z2 = z % p.bdiv;
  const __bf16* A = p.A + (long long)z1 * p.sAb1 + (long long)z2 * p.sAb2;
  const __bf16* B = p.B + (long long)z1 * p.sBb1 + (long long)z2 * p.sBb2;
  const int m0 = blockIdx.y * 128, n0 = blockIdx.x * 128;
  const int lane = t & 63, wave = t >> 6;
  const int wm = (wave >> 1) * 64, wn = (wave & 1) * 64;
  const int l15 = lane & 15, l4 = lane >> 4;
  f32x4 acc[4][4];
#pragma unroll
  for (int i = 0; i < 4; i++)
#pragma unroll
    for (int j = 0; j < 4; j++) acc[i][j] = f32x4{0.f, 0.f, 0.f, 0.f};

  int arow[4];
#pragma unroll
  for (int i = 0; i < 4; i++) {
    int slot = t + i * 256;
    arow[i] = min(m0 + (slot >> 3), p.M - 1);
  }
  for (int kb = 0; kb < p.K; kb += 64) {
#pragma unroll
    for (int i = 0; i < 4; i++) {
      int slot = t + i * 256;
      int r = slot >> 3, c = slot & 7;
      int gk = kb + c * 8;
      int4 v = make_int4(0, 0, 0, 0);
      if (gk < p.K) v = *(const int4*)(A + (long long)arow[i] * p.sAr + gk);
      *(int4*)&lA[r * 64 + (rot8(c, r & 7) << 3)] = v;
    }
#pragma unroll
    for (int i = 0; i < 4; i++) {
      int slot = t + i * 256;
      int kl = slot & 63, cch = slot >> 6;
      int gk = kb + kl;
      I4B8 u;
      u.i = make_int4(0, 0, 0, 0);
      if (gk < p.K) u.i = *(const int4*)(B + (long long)gk * p.sBr + n0 + cch * 8);
#pragma unroll
      for (int j = 0; j < 8; j++) {
        int n = cch * 8 + j;
        lB[n * 64 + (rot8(kl >> 3, n & 7) << 3) + (kl & 7)] = u.b[j];
      }
    }
    __syncthreads();
#pragma unroll
    for (int kk = 0; kk < 2; kk++) {
      bf8_t af[4], bfr[4];
      int cch = kk * 4 + l4;
#pragma unroll
      for (int mt = 0; mt < 4; mt++) {
        int r = wm + mt * 16 + l15;
        af[mt] = *(bf8_t*)&lA[r * 64 + (rot8(cch, r & 7) << 3)];
      }
#pragma unroll
      for (int nt = 0; nt < 4; nt++) {
        int r = wn + nt * 16 + l15;
        bfr[nt] = *(bf8_t*)&lB[r * 64 + (rot8(cch, r & 7) << 3)];
      }
#pragma unroll
      for (int mt = 0; mt < 4; mt++)
#pragma unroll
        for (int nt = 0; nt < 4; nt++)
          acc[mt][nt] = __builtin_amdgcn_mfma_f32_16x16x32_bf16(af[mt], bfr[nt], acc[mt][nt], 0, 0, 0);
    }
    __syncthreads();
  }
  long long coff = (long long)z1 * p.sCb1 + (long long)z2 * p.sCb2;
  float g = (p.mode == 2) ? *p.gma : 0.f;
#pragma unroll
  for (int nt = 0; nt < 4; nt++) {
    int col = n0 + wn + nt * 16 + l15;
    if (col >= p.N) continue;
#pragma unroll
    for (int mt = 0; mt < 4; mt++) {
      int row0 = m0 + wm + mt * 16 + (l4 << 2);
#pragma unroll
      for (int r = 0; r < 4; r++) {
        int row = row0 + r;
        if (row >= p.M) continue;
        long long offL = coff + (long long)row * p.sCr + col;
        long long offP = offL;
        if (CROT)
          offP = coff + (long long)row * p.sCr +
                 (col & ~63) + (rot8((col >> 3) & 7, row & 7) << 3) + (col & 7);
        float v = acc[mt][nt][r];
        if (p.mode == 2)
          v = g * ((float)p.tmp[offL] + v) + (float)p.res[offP];
        p.C[offP] = (__bf16)v;
      }
    }
  }
}

// ---------------------------------------------------------------- scores
__global__ __launch_bounds__(384) void cc_scores_k(const __bf16* qkv, float* attnf) {
  __shared__ __attribute__((aligned(16))) __bf16 Qs[96 * 64];
  __shared__ __attribute__((aligned(16))) __bf16 Ks[96 * 64];
  int bfi = blockIdx.x;
  int b = bfi / 96, f = bfi % 96;
  int mode = blockIdx.y;
  long long base = (mode == 0) ? ((long long)(b * 9216 + f)) * 640 : ((long long)(b * 9216 + f * 96)) * 640;
  long long rstr = (mode == 0) ? 96 * 640 : 640;
  int t = threadIdx.x;
#pragma unroll
  for (int i = 0; i < 2; i++) {
    int slot = t + i * 384;
    int r = slot >> 3, c = slot & 7;
    int sw = rot8(c, r & 7) << 3;
    *(int4*)&Qs[r * 64 + sw] = *(const int4*)(qkv + base + (long long)r * rstr + c * 8);
    *(int4*)&Ks[r * 64 + sw] = *(const int4*)(qkv + base + (long long)r * rstr + 64 + c * 8);
  }
  __syncthreads();
  int lane = t & 63, wave = t >> 6;
  int l15 = lane & 15, l4 = lane >> 4;
  f32x4 acc[6];
#pragma unroll
  for (int i = 0; i < 6; i++) acc[i] = f32x4{0.f, 0.f, 0.f, 0.f};
#pragma unroll
  for (int kk = 0; kk < 2; kk++) {
    int ar = wave * 16 + l15;
    int cch = kk * 4 + l4;
    bf8_t af = *(bf8_t*)&Qs[ar * 64 + (rot8(cch, ar & 7) << 3)];
#pragma unroll
    for (int nt = 0; nt < 6; nt++) {
      int br = nt * 16 + l15;
      bf8_t bfr = *(bf8_t*)&Ks[br * 64 + (rot8(cch, br & 7) << 3)];
      acc[nt] = __builtin_amdgcn_mfma_f32_16x16x32_bf16(af, bfr, acc[nt], 0, 0, 0);
    }
  }
#pragma unroll
  for (int nt = 0; nt < 6; nt++) {
#pragma unroll
    for (int r = 0; r < 4; r++) {
      int m = wave * 16 + (l4 << 2) + r;
      int n = nt * 16 + l15;
      float v = acc[nt][r];
      long long off;
      if (mode == 0) {
        if (n == m) v = -__builtin_inff();
        off = ((long long)((b * 96 + m) * 96 + f)) * 192 + n;
      } else {
        off = ((long long)((b * 96 + f) * 96 + m)) * 192 + 96 + n;
      }
      attnf[off] = v;
    }
  }
}

__global__ __launch_bounds__(256) void cc_softmax_k(const float* attnf, __bf16* attnb) {
  int wave = threadIdx.x >> 6, lane = threadIdx.x & 63;
  long long row = (long long)blockIdx.x * 4 + wave;
  const float* src = attnf + row * 192;
  float e0 = src[lane], e1 = src[lane + 64], e2 = src[lane + 128];
  float m = fmaxf(e0, fmaxf(e1, e2));
#pragma unroll
  for (int o = 32; o; o >>= 1) m = fmaxf(m, __shfl_xor(m, o));
  e0 = __expf(e0 - m);
  e1 = __expf(e1 - m);
  e2 = __expf(e2 - m);
  float s = e0 + e1 + e2;
#pragma unroll
  for (int o = 32; o; o >>= 1) s += __shfl_xor(s, o);
  float inv = 1.f / s;
  __bf16* dst = attnb + row * 192;
  dst[lane] = (__bf16)(e0 * inv);
  dst[lane + 64] = (__bf16)(e1 * inv);
  dst[lane + 128] = (__bf16)(e2 * inv);
}

// ---------------------------------------------------------------- conv3x3
// Both operands staged via global_load_lds. A rotation key = (w2+dx)&7 (baked
// into padb by pad_k); B rotation key = n&7 (baked by reorder_w_k).
__global__ __launch_bounds__(256) void conv3_gemm_k(const __bf16* pin, const __bf16* wr, __bf16* C) {
  __shared__ __attribute__((aligned(16))) __bf16 lA[128 * 64];
  __shared__ __attribute__((aligned(16))) __bf16 lB[128 * 64];
  const int t = threadIdx.x;
  const int id = blockIdx.x;
  const int per8 = gridDim.x >> 3;                 // 72
  const int lin = (id & 7) * per8 + (id >> 3);
  const int m0 = (lin >> 2) * 128, n0 = (lin & 3) * 128;   // m-major, ntn=4
  const int lane = t & 63, wave = t >> 6;
  const int wm = (wave >> 1) * 64, wn = (wave & 1) * 64;
  const int l15 = lane & 15, l4 = lane >> 4;
  const int srow = lane >> 3, schunk = (lane & 7) * 8;
  const int rb = wave * 32;
  f32x4 acc[4][4];
#pragma unroll
  for (int i = 0; i < 4; i++)
#pragma unroll
    for (int j = 0; j < 4; j++) acc[i][j] = f32x4{0.f, 0.f, 0.f, 0.f};
  // per-lane staging bases (pixel for A, weight-row for B)
  long long sbase[4], bbase[4];
#pragma unroll
  for (int i = 0; i < 4; i++) {
    int r = rb + i * 8 + srow;
    int m = m0 + r;
    int b = m / 9216, hw = m % 9216;
    int h = hw / 96, w2 = hw % 96;
    sbase[i] = ((long long)b * 9604 + h * 98 + w2) * 512 + schunk;
    bbase[i] = (long long)(n0 + r) * 4608 + schunk;
  }
  // A fragment-row w2 (for rotation key)
  int w2f[4];
#pragma unroll
  for (int mt = 0; mt < 4; mt++) w2f[mt] = (m0 + wm + mt * 16 + l15) % 96;

  int kt = 0;
  for (int tap = 0; tap < 9; tap++) {
    const int dy = tap / 3, dx = tap - dy * 3;
    const long long aoff = (long long)(dy * 98 + dx) * 512;
    int keyA[4];
#pragma unroll
    for (int mt = 0; mt < 4; mt++) keyA[mt] = (w2f[mt] + dx) & 7;
    for (int sl = 0; sl < 8; sl++, kt++) {
      const int c0k = sl * 64;
#pragma unroll
      for (int i = 0; i < 4; i++) {
        gload16(pin + sbase[i] + aoff + c0k, &lA[(rb + i * 8) * 64]);
        gload16(wr + bbase[i] + kt * 64, &lB[(rb + i * 8) * 64]);
      }
      __syncthreads();
#pragma unroll
      for (int kk = 0; kk < 2; kk++) {
        bf8_t af[4], bfr[4];
        int cch = kk * 4 + l4;
#pragma unroll
        for (int mt = 0; mt < 4; mt++) {
          int r = wm + mt * 16 + l15;
          af[mt] = *(bf8_t*)&lA[r * 64 + (rot8(cch, keyA[mt]) << 3)];
        }
#pragma unroll
        for (int nt = 0; nt < 4; nt++) {
          int r = wn + nt * 16 + l15;
          bfr[nt] = *(bf8_t*)&lB[r * 64 + (rot8(cch, r & 7) << 3)];
        }
#pragma unroll
        for (int mt = 0; mt < 4; mt++)
#pragma unroll
          for (int nt = 0; nt < 4; nt++)
            acc[mt][nt] = __builtin_amdgcn_mfma_f32_16x16x32_bf16(af[mt], bfr[nt], acc[mt][nt], 0, 0, 0);
      }
      __syncthreads();
    }
  }
#pragma unroll
  for (int nt = 0; nt < 4; nt++) {
    int col = n0 + wn + nt * 16 + l15;
#pragma unroll
    for (int mt = 0; mt < 4; mt++) {
      int row0 = m0 + wm + mt * 16 + (l4 << 2);
#pragma unroll
      for (int r = 0; r < 4; r++) {
        int row = row0 + r;
        C[(long long)row * 512 + col] = (__bf16)acc[mt][nt][r];
      }
    }
  }
}

// ---------------------------------------------------------------- GroupNorm
__global__ __launch_bounds__(256) void gn_stats_k(const __bf16* z, float* stats) {
  int bg = blockIdx.x;
  int b = bg >> 5, g = bg & 31;
  int t = threadIdx.x;
  int cch = t & 1, sp0 = t >> 1;
  const __bf16* base = z + (long long)b * 9216 * 512 + g * 16 + cch * 8;
  float s = 0.f, ss = 0.f;
  for (int sp = sp0; sp < 9216; sp += 128) {
    I4B8 u;
    u.i = *(const int4*)(base + (long long)sp * 512);
#pragma unroll
    for (int j = 0; j < 8; j++) {
      float f = (float)u.b[j];
      s += f;
      ss += f * f;
    }
  }
#pragma unroll
  for (int o = 32; o; o >>= 1) {
    s += __shfl_xor(s, o);
    ss += __shfl_xor(ss, o);
  }
  __shared__ float red[8];
  int wave = t >> 6, lane = t & 63;
  if (lane == 0) {
    red[wave] = s;
    red[4 + wave] = ss;
  }
  __syncthreads();
  if (t == 0) {
    float S = red[0] + red[1] + red[2] + red[3];
    float SS = red[4] + red[5] + red[6] + red[7];
    const float inv = 1.f / 147456.f;
    float mean = S * inv;
    float var = SS * inv - mean * mean;
    stats[2 * bg] = mean;
    stats[2 * bg + 1] = rsqrtf(var + 1e-5f);
  }
}

__global__ __launch_bounds__(256) void gn_write_k(const __bf16* z, const float* stats,
                                                 const float* gng, const float* gnb, float* out) {
  __shared__ __bf16 l[64 * 98];
  int c0 = blockIdx.x * 64, h = blockIdx.y, b = blockIdx.z;
  int t = threadIdx.x;
#pragma unroll
  for (int i = 0; i < 3; i++) {
    int slot = t + i * 256;
    int wl = slot >> 3, cch = slot & 7;
    I4B8 u;
    u.i = *(const int4*)(z + ((long long)(b * 9216 + h * 96 + wl)) * 512 + c0 + cch * 8);
#pragma unroll
    for (int j = 0; j < 8; j++) l[(cch * 8 + j) * 98 + wl] = u.b[j];
  }
  __syncthreads();
#pragma unroll
  for (int i = 0; i < 3; i++) {
    int slot = t + i * 256;
    int wch = slot % 12, cl = slot / 12;
    int c = c0 + cl;
    int g = c >> 4;
    float mean = stats[2 * (b * 32 + g)], rstd = stats[2 * (b * 32 + g) + 1];
    float sc = rstd * gng[c];
    float sh = gnb[c] - mean * sc;
    float4 o0, o1;
    const __bf16* src = &l[cl * 98 + wch * 8];
    o0.x = (float)src[0] * sc + sh; o0.y = (float)src[1] * sc + sh;
    o0.z = (float)src[2] * sc + sh; o0.w = (float)src[3] * sc + sh;
    o1.x = (float)src[4] * sc + sh; o1.y = (float)src[5] * sc + sh;
    o1.z = (float)src[6] * sc + sh; o1.w = (float)src[7] * sc + sh;
    float* dst = out + ((long long)((b * 512 + c) * 96 + h)) * 96 + wch * 8;
    *(float4*)dst = o0;
    *(float4*)(dst + 4) = o1;
  }
}

// ---------------------------------------------------------------- launch
extern "C" void kernel_launch(void* const* d_in, const int* in_sizes, int n_in,
                              void* d_out, int out_size, void* d_ws, size_t ws_size,
                              hipStream_t stream) {
  (void)in_sizes; (void)n_in; (void)out_size;
  const float* x = (const float*)d_in[0];
  const float* conv1w = (const float*)d_in[1];
  const float* conv1b = (const float*)d_in[2];
  const float* qw = (const float*)d_in[3];
  const float* qbias = (const float*)d_in[4];
  const float* kw = (const float*)d_in[5];
  const float* kbias = (const float*)d_in[6];
  const float* vw = (const float*)d_in[7];
  const float* vbias = (const float*)d_in[8];
  const float* gma = (const float*)d_in[9];
  const float* cow = (const float*)d_in[10];
  const float* gng = (const float*)d_in[11];
  const float* gnb = (const float*)d_in[12];
  float* out = (float*)d_out;

  if (ws_size < 134876160ULL) return;

  char* w = (char*)d_ws;
  __bf16* xt    = (__bf16*)(w);                 // 75,497,472
  __bf16* qkv   = (__bf16*)(w);                 // 23,592,960
  __bf16* attnb = (__bf16*)(w + 23592960);      // 7,077,888
  __bf16* padb  = (__bf16*)(w);                 // 19,668,992
  __bf16* zb    = (__bf16*)(w + 19668992);      // 18,874,368
  __bf16* wrot  = (__bf16*)(w + 38543360);      // 4,718,592
  __bf16* ya    = (__bf16*)(w + 75497472);      // 18,874,368
  __bf16* yb    = (__bf16*)(w + 94371840);      // 18,874,368
  __bf16* tmp1  = (__bf16*)(w + 113246208);     // 18,874,368 (attnf aliases)
  float* attnf  = (float*)(w + 113246208);      // 14,155,776
  __bf16* c1wb  = (__bf16*)(w + 132120576);     // 2,097,152
  __bf16* wqkvb = (__bf16*)(w + 134217728);     // 655,360
  float* qkvbias = (float*)(w + 134873088);     // 2,560
  float* stats   = (float*)(w + 134875648);     // 512

  cast_rot_k<<<512, 256, 0, stream>>>(conv1w, c1wb, 256, 131072);
  wqkv_rot_k<<<160, 256, 0, stream>>>(qw, kw, vw, wqkvb);
  fuse_bias_k<<<3, 256, 0, stream>>>(qbias, kbias, vbias, qkvbias);
  transpose_x_k<<<dim3(32, 144, 2), 256, 0, stream>>>(x, xt);

  {  // conv1: ya = xt @ c1wb^T + b (rotated out)
    GemmAP p{};
    p.A = xt; p.B = c1wb; p.C = ya; p.bias = conv1b;
    p.sAr = 2048; p.sBr = 2048; p.sCr = 512;
    p.K = 2048; p.ntn = 4;
    gemm_async_k<1><<<576, 256, 0, stream>>>(p);
  }

  for (int it = 0; it < 2; it++) {
    __bf16* tin = it ? yb : ya;
    __bf16* tout = it ? ya : yb;
    {  // fused qkv projection
      GemmAP p{};
      p.A = tin; p.B = wqkvb; p.C = qkv; p.bias = qkvbias;
      p.sAr = 512; p.sBr = 512; p.sCr = 640;
      p.K = 512; p.ntn = 5;
      gemm_async_k<0><<<720, 256, 0, stream>>>(p);
    }
    cc_scores_k<<<dim3(192, 2), 384, 0, stream>>>(qkv, attnf);
    cc_softmax_k<<<4608, 256, 0, stream>>>(attnf, attnb);
    {  // agg1: per (b,w): tmp1[h,c] = sum_i a_h[h,i] * v[b,i,w,c]
      GemmP p{};
      p.A = attnb; p.sAr = 96 * 192; p.sAb1 = (long long)96 * 96 * 192; p.sAb2 = 192;
      p.B = qkv + 128; p.sBr = (long long)96 * 640; p.sBb1 = (long long)9216 * 640; p.sBb2 = 640;
      p.C = tmp1; p.sCr = (long long)96 * 512; p.sCb1 = (long long)9216 * 512; p.sCb2 = 512;
      p.M = 96; p.N = 512; p.K = 96; p.bdiv = 96; p.mode = 0;
      gemm_bt_k<0><<<dim3(4, 1, 192), 256, 0, stream>>>(p);
    }
    {  // agg2 + epilogue (rotated out/res)
      GemmP p{};
      p.A = attnb + 96; p.sAr = 192; p.sAb1 = (long long)96 * 96 * 192; p.sAb2 = (long long)96 * 192;
      p.B = qkv + 128; p.sBr = 640; p.sBb1 = (long long)9216 * 640; p.sBb2 = (long long)96 * 640;
      p.C = tout; p.sCr = 512; p.sCb1 = (long long)9216 * 512; p.sCb2 = (long long)96 * 512;
      p.M = 96; p.N = 512; p.K = 96; p.bdiv = 96; p.mode = 2;
      p.tmp = tmp1; p.res = tin; p.gma = gma;
      gemm_bt_k<1><<<dim3(4, 1, 192), 256, 0, stream>>>(p);
    }
  }

  reorder_w_k<<<1152, 256, 0, stream>>>(cow, wrot);
  pad_k<<<4802, 256, 0, stream>>>(ya, padb);  // final attention output is in ya
  conv3_gemm_k<<<576, 256, 0, stream>>>(padb, wrot, zb);
  gn_stats_k<<<64, 256, 0, stream>>>(zb, stats);
  gn_write_k<<<dim3(8, 96, 2), 256, 0, stream>>>(zb, stats, gng, gnb, out);
}

// Round 5
// 660.881 us; speedup vs baseline: 1.3589x; 1.0488x over previous
//
#include <hip/hip_runtime.h>
#include <hip/hip_bf16.h>

// CCAttention pipeline on MI355X. fp32 in/out, bf16 MFMA internal, NHWC.
// B=2, CIN=2048, CINT=512, CQK=64, H=W=96, S=9216, NG=32.
// R5: scores write contiguous attnfH/attnfW; softmax writes padded+rotated
// a_h/a_w (K=128) -> agg GEMMs use async A-staging; agg2(it=1) writes padb
// directly (pad_k removed, border-zero kernel added); coalesced reorder_w.

typedef __bf16 bf8_t __attribute__((ext_vector_type(8)));
typedef float f32x4 __attribute__((ext_vector_type(4)));

union I4B8 { int4 i; bf8_t b; };

typedef const __attribute__((address_space(1))) void as1_cvoid;
typedef __attribute__((address_space(3))) void as3_void;
__device__ __forceinline__ void gload16(const void* g, void* l) {
  __builtin_amdgcn_global_load_lds((as1_cvoid*)g, (as3_void*)l, 16, 0, 0);
}
__device__ __forceinline__ int rot8(int c, int key) { return (c + key) & 7; }

// ---------------------------------------------------------------- weight prep
__global__ __launch_bounds__(256) void cast_rot_k(const float* s, __bf16* d, int K8, int total8) {
  int idx = blockIdx.x * 256 + threadIdx.x;
  if (idx >= total8) return;
  int c8 = idx % K8, n = idx / K8;
  int pos = rot8(c8 & 7, n & 7);
  const float* sp = s + ((long long)n * K8 + c8) * 8;
  float4 a = *(const float4*)sp, b = *(const float4*)(sp + 4);
  I4B8 u;
  u.b[0] = (__bf16)a.x; u.b[1] = (__bf16)a.y; u.b[2] = (__bf16)a.z; u.b[3] = (__bf16)a.w;
  u.b[4] = (__bf16)b.x; u.b[5] = (__bf16)b.y; u.b[6] = (__bf16)b.z; u.b[7] = (__bf16)b.w;
  *(int4*)(d + ((long long)n * K8 + (c8 & ~7) + pos) * 8) = u.i;
}

__global__ __launch_bounds__(256) void wqkv_rot_k(const float* qw, const float* kw, const float* vw, __bf16* d) {
  int idx = blockIdx.x * 256 + threadIdx.x;  // 640*64
  if (idx >= 640 * 64) return;
  int c8 = idx & 63, n = idx >> 6;
  const float* src = (n < 64) ? qw + (long long)n * 512
                   : (n < 128) ? kw + (long long)(n - 64) * 512
                               : vw + (long long)(n - 128) * 512;
  int pos = rot8(c8 & 7, n & 7);
  const float* sp = src + c8 * 8;
  float4 a = *(const float4*)sp, b = *(const float4*)(sp + 4);
  I4B8 u;
  u.b[0] = (__bf16)a.x; u.b[1] = (__bf16)a.y; u.b[2] = (__bf16)a.z; u.b[3] = (__bf16)a.w;
  u.b[4] = (__bf16)b.x; u.b[5] = (__bf16)b.y; u.b[6] = (__bf16)b.z; u.b[7] = (__bf16)b.w;
  *(int4*)(d + ((long long)n * 64 + (c8 & ~7) + pos) * 8) = u.i;
}

__global__ __launch_bounds__(256) void fuse_bias_k(const float* qb, const float* kb, const float* vb, float* d) {
  int i = blockIdx.x * 256 + threadIdx.x;
  if (i >= 640) return;
  d[i] = (i < 64) ? qb[i] : (i < 128) ? kb[i - 64] : vb[i - 128];
}

// conv3 weights -> wr[o][dydx*512+c] rotated by o&7; coalesced via LDS.
__global__ __launch_bounds__(256) void reorder_w_k(const float* w, __bf16* wr) {
  __shared__ float ls[4608];
  int o = blockIdx.x;
  int t = threadIdx.x;
  const float* base = w + (long long)o * 4608;
#pragma unroll
  for (int i = 0; i < 18; i++) ls[t + i * 256] = base[t + i * 256];
  __syncthreads();
#pragma unroll
  for (int i = 0; i < 3; i++) {
    int q = t + i * 256;
    if (q >= 576) break;
    int k0 = q * 8;
    int dydx = k0 / 512, c0 = k0 & 511;
    I4B8 u;
#pragma unroll
    for (int j = 0; j < 8; j++) u.b[j] = (__bf16)ls[(c0 + j) * 9 + dydx];
    int pos = rot8((k0 >> 3) & 7, o & 7);
    *(int4*)(wr + (long long)o * 4608 + (k0 & ~63) + pos * 8) = u.i;
  }
}

// x f32 NCHW -> xt bf16 NHWC, rotated by pixel&7.
__global__ __launch_bounds__(256) void transpose_x_k(const float* x, __bf16* xt) {
  __shared__ __bf16 l[64 * 66];
  int c0 = blockIdx.x * 64, s0 = blockIdx.y * 64, b = blockIdx.z;
  int t = threadIdx.x;
#pragma unroll
  for (int i = 0; i < 2; i++) {
    int slot = t + i * 256;
    int cl = slot >> 3, sch = slot & 7;
    const float* src = x + ((long long)(b * 2048 + c0 + cl)) * 9216 + s0 + sch * 8;
    float4 a = *(const float4*)src, bb = *(const float4*)(src + 4);
    __bf16* dst = &l[cl * 66 + sch * 8];
    dst[0] = (__bf16)a.x; dst[1] = (__bf16)a.y; dst[2] = (__bf16)a.z; dst[3] = (__bf16)a.w;
    dst[4] = (__bf16)bb.x; dst[5] = (__bf16)bb.y; dst[6] = (__bf16)bb.z; dst[7] = (__bf16)bb.w;
  }
  __syncthreads();
#pragma unroll
  for (int i = 0; i < 2; i++) {
    int slot = t + i * 256;
    int sl = slot >> 3, cch = slot & 7;
    I4B8 u;
#pragma unroll
    for (int j = 0; j < 8; j++) u.b[j] = l[(cch * 8 + j) * 66 + sl];
    *(int4*)(xt + ((long long)(b * 9216 + s0 + sl)) * 2048 + c0 + rot8(cch, sl & 7) * 8) = u.i;
  }
}

// zero the padb border pixels (interior is written by agg2 it=1)
__global__ __launch_bounds__(256) void border0_k(__bf16* padb) {
  int idx = blockIdx.x * 256 + threadIdx.x;  // 776 border pixels * 64 int4
  if (idx >= 776 * 64) return;
  int ch = idx & 63, bi = idx >> 6;
  int b = bi / 388, r = bi % 388;
  int hh, ww;
  if (r < 98) { hh = 0; ww = r; }
  else if (r < 196) { hh = 97; ww = r - 98; }
  else if (r < 292) { hh = r - 196 + 1; ww = 0; }
  else { hh = r - 292 + 1; ww = 97; }
  *(int4*)(padb + ((long long)(b * 9604 + hh * 98 + ww)) * 512 + ch * 8) = make_int4(0, 0, 0, 0);
}

// ---------------------------------------------------------------- async GEMM
struct GemmAP {
  const __bf16 *A, *B;
  __bf16* C;
  const float* bias;
  long long sAr, sBr, sCr;
  int K, ntn;
};

template <int CROT>
__global__ __launch_bounds__(256) void gemm_async_k(GemmAP p) {
  __shared__ __attribute__((aligned(16))) __bf16 lA[128 * 64];
  __shared__ __attribute__((aligned(16))) __bf16 lB[128 * 64];
  const int t = threadIdx.x;
  const int id = blockIdx.x;
  const int per8 = gridDim.x >> 3;
  const int lin = (id & 7) * per8 + (id >> 3);
  const int m0 = (lin / p.ntn) * 128, n0 = (lin % p.ntn) * 128;
  const int lane = t & 63, wave = t >> 6;
  const int wm = (wave >> 1) * 64, wn = (wave & 1) * 64;
  const int l15 = lane & 15, l4 = lane >> 4;
  const int srow = (lane >> 3), schunk = (lane & 7) * 8;
  f32x4 acc[4][4];
#pragma unroll
  for (int i = 0; i < 4; i++)
#pragma unroll
    for (int j = 0; j < 4; j++) acc[i][j] = f32x4{0.f, 0.f, 0.f, 0.f};

  for (int kb = 0; kb < p.K; kb += 64) {
    const int rb = wave * 32;
#pragma unroll
    for (int i = 0; i < 4; i++) {
      int row = rb + i * 8;
      gload16(p.A + (long long)(m0 + row + srow) * p.sAr + kb + schunk, &lA[row * 64]);
      gload16(p.B + (long long)(n0 + row + srow) * p.sBr + kb + schunk, &lB[row * 64]);
    }
    __syncthreads();
#pragma unroll
    for (int kk = 0; kk < 2; kk++) {
      bf8_t af[4], bfr[4];
      int cch = kk * 4 + l4;
#pragma unroll
      for (int mt = 0; mt < 4; mt++) {
        int r = wm + mt * 16 + l15;
        af[mt] = *(bf8_t*)&lA[r * 64 + (rot8(cch, r & 7) << 3)];
      }
#pragma unroll
      for (int nt = 0; nt < 4; nt++) {
        int r = wn + nt * 16 + l15;
        bfr[nt] = *(bf8_t*)&lB[r * 64 + (rot8(cch, r & 7) << 3)];
      }
#pragma unroll
      for (int mt = 0; mt < 4; mt++)
#pragma unroll
        for (int nt = 0; nt < 4; nt++)
          acc[mt][nt] = __builtin_amdgcn_mfma_f32_16x16x32_bf16(af[mt], bfr[nt], acc[mt][nt], 0, 0, 0);
    }
    __syncthreads();
  }
#pragma unroll
  for (int nt = 0; nt < 4; nt++) {
    int col = n0 + wn + nt * 16 + l15;
    float bv = p.bias[col];
#pragma unroll
    for (int mt = 0; mt < 4; mt++) {
      int row0 = m0 + wm + mt * 16 + (l4 << 2);
#pragma unroll
      for (int r = 0; r < 4; r++) {
        int row = row0 + r;
        int pc = CROT ? (col & ~63) + (rot8((col >> 3) & 7, row & 7) << 3) + (col & 7) : col;
        p.C[(long long)row * p.sCr + pc] = (__bf16)(acc[mt][nt][r] + bv);
      }
    }
  }
}

// ---------------------------------------------------------------- agg GEMM
// Batched 96(M)x512(N)x128(Kpad) GEMM. A (a_h/a_w): rows pre-rotated (key
// row&7), padded K=128, batch stride 96*128 -> async staging. B: V section
// of qkv, transposed-in-LDS (k rows, guard k<96 -> zeros).
// MODE 0: C=acc (tmp1). MODE 1: C[rot]=g*(tmp+acc)+res. MODE 2: same but
// store into padb at (h+1,w+1) with key (w+1)&7.
struct AggP {
  const __bf16 *A, *B;  // B = qkv + 128 (V columns)
  __bf16* C;
  const __bf16 *tmp, *res;
  const float* gma;
  long long bB1, bB2, sBr;
  long long cB1, cB2, sCr;
};

template <int MODE>
__global__ __launch_bounds__(256) void agg_k(AggP p) {
  __shared__ __attribute__((aligned(16))) __bf16 lA[128 * 64];
  __shared__ __attribute__((aligned(16))) __bf16 lB[128 * 64];
  const int t = threadIdx.x;
  const int z = blockIdx.z;
  const int z1 = z / 96, z2 = z % 96;
  const __bf16* A = p.A + (long long)z * (96 * 128);
  const __bf16* B = p.B + (long long)z1 * p.bB1 + (long long)z2 * p.bB2;
  const int n0 = blockIdx.x * 128;
  const int lane = t & 63, wave = t >> 6;
  const int wm = (wave >> 1) * 64, wn = (wave & 1) * 64;
  const int l15 = lane & 15, l4 = lane >> 4;
  const int srow = lane >> 3, schunk = (lane & 7) * 8;
  f32x4 acc[4][4];
#pragma unroll
  for (int i = 0; i < 4; i++)
#pragma unroll
    for (int j = 0; j < 4; j++) acc[i][j] = f32x4{0.f, 0.f, 0.f, 0.f};

#pragma unroll
  for (int kb = 0; kb < 128; kb += 64) {
    const int rb = wave * 32;
#pragma unroll
    for (int i = 0; i < 4; i++) {
      int row = rb + i * 8;
      gload16(A + (long long)(row + srow) * 128 + kb + schunk, &lA[row * 64]);
    }
#pragma unroll
    for (int i = 0; i < 4; i++) {
      int slot = t + i * 256;
      int kl = slot & 63, cch = slot >> 6;
      int gk = kb + kl;
      I4B8 u;
      u.i = make_int4(0, 0, 0, 0);
      if (gk < 96) u.i = *(const int4*)(B + (long long)gk * p.sBr + n0 + cch * 8);
#pragma unroll
      for (int j = 0; j < 8; j++) {
        int n = cch * 8 + j;
        lB[n * 64 + (rot8(kl >> 3, n & 7) << 3) + (kl & 7)] = u.b[j];
      }
    }
    __syncthreads();
#pragma unroll
    for (int kk = 0; kk < 2; kk++) {
      bf8_t af[4], bfr[4];
      int cch = kk * 4 + l4;
#pragma unroll
      for (int mt = 0; mt < 4; mt++) {
        int r = wm + mt * 16 + l15;
        af[mt] = *(bf8_t*)&lA[r * 64 + (rot8(cch, r & 7) << 3)];
      }
#pragma unroll
      for (int nt = 0; nt < 4; nt++) {
        int r = wn + nt * 16 + l15;
        bfr[nt] = *(bf8_t*)&lB[r * 64 + (rot8(cch, r & 7) << 3)];
      }
#pragma unroll
      for (int mt = 0; mt < 4; mt++)
#pragma unroll
        for (int nt = 0; nt < 4; nt++)
          acc[mt][nt] = __builtin_amdgcn_mfma_f32_16x16x32_bf16(af[mt], bfr[nt], acc[mt][nt], 0, 0, 0);
    }
    __syncthreads();
  }
  long long cbase = (long long)z1 * p.cB1 + (long long)z2 * p.cB2;
  float g = MODE ? *p.gma : 0.f;
#pragma unroll
  for (int nt = 0; nt < 4; nt++) {
    int col = n0 + wn + nt * 16 + l15;
#pragma unroll
    for (int mt = 0; mt < 4; mt++) {
      int row0 = wm + mt * 16 + (l4 << 2);
#pragma unroll
      for (int r = 0; r < 4; r++) {
        int row = row0 + r;
        if (row >= 96) continue;
        long long offL = cbase + (long long)row * p.sCr + col;
        float v = acc[mt][nt][r];
        if (MODE == 0) {
          p.C[offL] = (__bf16)v;
        } else {
          int rc = (col & ~63) + (rot8((col >> 3) & 7, row & 7) << 3) + (col & 7);
          long long offP = cbase + (long long)row * p.sCr + rc;
          v = g * ((float)p.tmp[offL] + v) + (float)p.res[offP];
          if (MODE == 1) {
            p.C[offP] = (__bf16)v;
          } else {
            int pc = (col & ~63) + (rot8((col >> 3) & 7, (row + 1) & 7) << 3) + (col & 7);
            long long pidx = (long long)z1 * 9604 + (long long)(z2 + 1) * 98 + (row + 1);
            p.C[pidx * 512 + pc] = (__bf16)v;
          }
        }
      }
    }
  }
}

// ---------------------------------------------------------------- scores
// mode 0 (b,w): E[h][i] (diag -inf) -> attnfH[b*96+w][h*96+i]
// mode 1 (b,h): E[w][j]             -> attnfW[b*96+h][w*96+j]
__global__ __launch_bounds__(384) void cc_scores_k(const __bf16* qkv, float* attnfH, float* attnfW) {
  __shared__ __attribute__((aligned(16))) __bf16 Qs[96 * 64];
  __shared__ __attribute__((aligned(16))) __bf16 Ks[96 * 64];
  int bfi = blockIdx.x;
  int b = bfi / 96, f = bfi % 96;
  int mode = blockIdx.y;
  long long base = (mode == 0) ? ((long long)(b * 9216 + f)) * 640 : ((long long)(b * 9216 + f * 96)) * 640;
  long long rstr = (mode == 0) ? 96 * 640 : 640;
  int t = threadIdx.x;
#pragma unroll
  for (int i = 0; i < 2; i++) {
    int slot = t + i * 384;
    int r = slot >> 3, c = slot & 7;
    int sw = rot8(c, r & 7) << 3;
    *(int4*)&Qs[r * 64 + sw] = *(const int4*)(qkv + base + (long long)r * rstr + c * 8);
    *(int4*)&Ks[r * 64 + sw] = *(const int4*)(qkv + base + (long long)r * rstr + 64 + c * 8);
  }
  __syncthreads();
  int lane = t & 63, wave = t >> 6;
  int l15 = lane & 15, l4 = lane >> 4;
  f32x4 acc[6];
#pragma unroll
  for (int i = 0; i < 6; i++) acc[i] = f32x4{0.f, 0.f, 0.f, 0.f};
#pragma unroll
  for (int kk = 0; kk < 2; kk++) {
    int ar = wave * 16 + l15;
    int cch = kk * 4 + l4;
    bf8_t af = *(bf8_t*)&Qs[ar * 64 + (rot8(cch, ar & 7) << 3)];
#pragma unroll
    for (int nt = 0; nt < 6; nt++) {
      int br = nt * 16 + l15;
      bf8_t bfr = *(bf8_t*)&Ks[br * 64 + (rot8(cch, br & 7) << 3)];
      acc[nt] = __builtin_amdgcn_mfma_f32_16x16x32_bf16(af, bfr, acc[nt], 0, 0, 0);
    }
  }
  float* dst = (mode == 0 ? attnfH : attnfW) + (long long)bfi * 9216;
#pragma unroll
  for (int nt = 0; nt < 6; nt++) {
#pragma unroll
    for (int r = 0; r < 4; r++) {
      int m = wave * 16 + (l4 << 2) + r;
      int n = nt * 16 + l15;
      float v = acc[nt][r];
      if (mode == 0 && n == m) v = -__builtin_inff();
      dst[m * 96 + n] = v;
    }
  }
}

// softmax over concat[e_h, e_w] (192), writes padded+rotated a_h/a_w rows.
__global__ __launch_bounds__(256) void cc_softmax_k(const float* attnfH, const float* attnfW,
                                                    __bf16* a_h, __bf16* a_w) {
  int wave = threadIdx.x >> 6, lane = threadIdx.x & 63;
  int pix = blockIdx.x * 4 + wave;
  int b = pix / 9216, hw = pix % 9216;
  int h = hw / 96, w2 = hw % 96;
  const float* ehb = attnfH + ((long long)(b * 96 + w2)) * 9216 + h * 96;
  const float* ewb = attnfW + ((long long)(b * 96 + h)) * 9216 + w2 * 96;
  float x0 = ehb[lane];
  float x1 = lane < 32 ? ehb[64 + lane] : -__builtin_inff();
  float x2 = ewb[lane];
  float x3 = lane < 32 ? ewb[64 + lane] : -__builtin_inff();
  float m = fmaxf(fmaxf(x0, x1), fmaxf(x2, x3));
#pragma unroll
  for (int o = 32; o; o >>= 1) m = fmaxf(m, __shfl_xor(m, o));
  float e0 = __expf(x0 - m), e1 = __expf(x1 - m), e2 = __expf(x2 - m), e3 = __expf(x3 - m);
  float s = e0 + e1 + e2 + e3;
#pragma unroll
  for (int o = 32; o; o >>= 1) s += __shfl_xor(s, o);
  float inv = 1.f / s;
  // a_h row (h), key h&7 ; a_w row (w2), key w2&7
  __bf16* dh = a_h + ((long long)((b * 96 + w2) * 96 + h)) * 128;
  __bf16* dw = a_w + ((long long)((b * 96 + h) * 96 + w2)) * 128;
  int kh = h & 7, kw2 = w2 & 7;
  int k1 = lane, k2 = 64 + lane;
  int p1h = (k1 & ~63) + (rot8((k1 >> 3) & 7, kh) << 3) + (k1 & 7);
  int p2h = (k2 & ~63) + (rot8((k2 >> 3) & 7, kh) << 3) + (k2 & 7);
  int p1w = (k1 & ~63) + (rot8((k1 >> 3) & 7, kw2) << 3) + (k1 & 7);
  int p2w = (k2 & ~63) + (rot8((k2 >> 3) & 7, kw2) << 3) + (k2 & 7);
  dh[p1h] = (__bf16)(e0 * inv);
  dh[p2h] = (__bf16)(lane < 32 ? e1 * inv : 0.f);
  dw[p1w] = (__bf16)(e2 * inv);
  dw[p2w] = (__bf16)(lane < 32 ? e3 * inv : 0.f);
}

// ---------------------------------------------------------------- conv3x3
__global__ __launch_bounds__(256) void conv3_gemm_k(const __bf16* pin, const __bf16* wr, __bf16* C) {
  __shared__ __attribute__((aligned(16))) __bf16 lA[128 * 64];
  __shared__ __attribute__((aligned(16))) __bf16 lB[128 * 64];
  const int t = threadIdx.x;
  const int id = blockIdx.x;
  const int per8 = gridDim.x >> 3;                 // 72
  const int lin = (id & 7) * per8 + (id >> 3);
  const int m0 = (lin >> 2) * 128, n0 = (lin & 3) * 128;
  const int lane = t & 63, wave = t >> 6;
  const int wm = (wave >> 1) * 64, wn = (wave & 1) * 64;
  const int l15 = lane & 15, l4 = lane >> 4;
  const int srow = lane >> 3, schunk = (lane & 7) * 8;
  const int rb = wave * 32;
  f32x4 acc[4][4];
#pragma unroll
  for (int i = 0; i < 4; i++)
#pragma unroll
    for (int j = 0; j < 4; j++) acc[i][j] = f32x4{0.f, 0.f, 0.f, 0.f};
  long long sbase[4], bbase[4];
#pragma unroll
  for (int i = 0; i < 4; i++) {
    int r = rb + i * 8 + srow;
    int m = m0 + r;
    int b = m / 9216, hw = m % 9216;
    int h = hw / 96, w2 = hw % 96;
    sbase[i] = ((long long)b * 9604 + h * 98 + w2) * 512 + schunk;
    bbase[i] = (long long)(n0 + r) * 4608 + schunk;
  }
  int w2f[4];
#pragma unroll
  for (int mt = 0; mt < 4; mt++) w2f[mt] = (m0 + wm + mt * 16 + l15) % 96;

  int kt = 0;
  for (int tap = 0; tap < 9; tap++) {
    const int dy = tap / 3, dx = tap - dy * 3;
    const long long aoff = (long long)(dy * 98 + dx) * 512;
    int keyA[4];
#pragma unroll
    for (int mt = 0; mt < 4; mt++) keyA[mt] = (w2f[mt] + dx) & 7;
    for (int sl = 0; sl < 8; sl++, kt++) {
      const int c0k = sl * 64;
#pragma unroll
      for (int i = 0; i < 4; i++) {
        gload16(pin + sbase[i] + aoff + c0k, &lA[(rb + i * 8) * 64]);
        gload16(wr + bbase[i] + kt * 64, &lB[(rb + i * 8) * 64]);
      }
      __syncthreads();
#pragma unroll
      for (int kk = 0; kk < 2; kk++) {
        bf8_t af[4], bfr[4];
        int cch = kk * 4 + l4;
#pragma unroll
        for (int mt = 0; mt < 4; mt++) {
          int r = wm + mt * 16 + l15;
          af[mt] = *(bf8_t*)&lA[r * 64 + (rot8(cch, keyA[mt]) << 3)];
        }
#pragma unroll
        for (int nt = 0; nt < 4; nt++) {
          int r = wn + nt * 16 + l15;
          bfr[nt] = *(bf8_t*)&lB[r * 64 + (rot8(cch, r & 7) << 3)];
        }
#pragma unroll
        for (int mt = 0; mt < 4; mt++)
#pragma unroll
          for (int nt = 0; nt < 4; nt++)
            acc[mt][nt] = __builtin_amdgcn_mfma_f32_16x16x32_bf16(af[mt], bfr[nt], acc[mt][nt], 0, 0, 0);
      }
      __syncthreads();
    }
  }
#pragma unroll
  for (int nt = 0; nt < 4; nt++) {
    int col = n0 + wn + nt * 16 + l15;
#pragma unroll
    for (int mt = 0; mt < 4; mt++) {
      int row0 = m0 + wm + mt * 16 + (l4 << 2);
#pragma unroll
      for (int r = 0; r < 4; r++) {
        int row = row0 + r;
        C[(long long)row * 512 + col] = (__bf16)acc[mt][nt][r];
      }
    }
  }
}

// ---------------------------------------------------------------- GroupNorm
__global__ __launch_bounds__(256) void gn_stats_k(const __bf16* z, float* stats) {
  int bg = blockIdx.x;
  int b = bg >> 5, g = bg & 31;
  int t = threadIdx.x;
  int cch = t & 1, sp0 = t >> 1;
  const __bf16* base = z + (long long)b * 9216 * 512 + g * 16 + cch * 8;
  float s = 0.f, ss = 0.f;
  for (int sp = sp0; sp < 9216; sp += 128) {
    I4B8 u;
    u.i = *(const int4*)(base + (long long)sp * 512);
#pragma unroll
    for (int j = 0; j < 8; j++) {
      float f = (float)u.b[j];
      s += f;
      ss += f * f;
    }
  }
#pragma unroll
  for (int o = 32; o; o >>= 1) {
    s += __shfl_xor(s, o);
    ss += __shfl_xor(ss, o);
  }
  __shared__ float red[8];
  int wave = t >> 6, lane = t & 63;
  if (lane == 0) {
    red[wave] = s;
    red[4 + wave] = ss;
  }
  __syncthreads();
  if (t == 0) {
    float S = red[0] + red[1] + red[2] + red[3];
    float SS = red[4] + red[5] + red[6] + red[7];
    const float inv = 1.f / 147456.f;
    float mean = S * inv;
    float var = SS * inv - mean * mean;
    stats[2 * bg] = mean;
    stats[2 * bg + 1] = rsqrtf(var + 1e-5f);
  }
}

__global__ __launch_bounds__(256) void gn_write_k(const __bf16* z, const float* stats,
                                                 const float* gng, const float* gnb, float* out) {
  __shared__ __bf16 l[64 * 98];
  int c0 = blockIdx.x * 64, h = blockIdx.y, b = blockIdx.z;
  int t = threadIdx.x;
#pragma unroll
  for (int i = 0; i < 3; i++) {
    int slot = t + i * 256;
    int wl = slot >> 3, cch = slot & 7;
    I4B8 u;
    u.i = *(const int4*)(z + ((long long)(b * 9216 + h * 96 + wl)) * 512 + c0 + cch * 8);
#pragma unroll
    for (int j = 0; j < 8; j++) l[(cch * 8 + j) * 98 + wl] = u.b[j];
  }
  __syncthreads();
#pragma unroll
  for (int i = 0; i < 3; i++) {
    int slot = t + i * 256;
    int wch = slot % 12, cl = slot / 12;
    int c = c0 + cl;
    int g = c >> 4;
    float mean = stats[2 * (b * 32 + g)], rstd = stats[2 * (b * 32 + g) + 1];
    float sc = rstd * gng[c];
    float sh = gnb[c] - mean * sc;
    float4 o0, o1;
    const __bf16* src = &l[cl * 98 + wch * 8];
    o0.x = (float)src[0] * sc + sh; o0.y = (float)src[1] * sc + sh;
    o0.z = (float)src[2] * sc + sh; o0.w = (float)src[3] * sc + sh;
    o1.x = (float)src[4] * sc + sh; o1.y = (float)src[5] * sc + sh;
    o1.z = (float)src[6] * sc + sh; o1.w = (float)src[7] * sc + sh;
    float* dst = out + ((long long)((b * 512 + c) * 96 + h)) * 96 + wch * 8;
    *(float4*)dst = o0;
    *(float4*)(dst + 4) = o1;
  }
}

// ---------------------------------------------------------------- launch
extern "C" void kernel_launch(void* const* d_in, const int* in_sizes, int n_in,
                              void* d_out, int out_size, void* d_ws, size_t ws_size,
                              hipStream_t stream) {
  (void)in_sizes; (void)n_in; (void)out_size;
  const float* x = (const float*)d_in[0];
  const float* conv1w = (const float*)d_in[1];
  const float* conv1b = (const float*)d_in[2];
  const float* qw = (const float*)d_in[3];
  const float* qbias = (const float*)d_in[4];
  const float* kw = (const float*)d_in[5];
  const float* kbias = (const float*)d_in[6];
  const float* vw = (const float*)d_in[7];
  const float* vbias = (const float*)d_in[8];
  const float* gma = (const float*)d_in[9];
  const float* cow = (const float*)d_in[10];
  const float* gng = (const float*)d_in[11];
  const float* gnb = (const float*)d_in[12];
  float* out = (float*)d_out;

  if (ws_size < 134876160ULL) return;

  char* w = (char*)d_ws;
  __bf16* xt     = (__bf16*)(w);                 // 75,497,472 (phase 1)
  __bf16* qkv    = (__bf16*)(w);                 // 23,592,960
  float* attnfH  = (float*)(w + 23592960);       // 7,077,888
  float* attnfW  = (float*)(w + 30670848);       // 7,077,888
  __bf16* a_h    = (__bf16*)(w + 37748736);      // 4,718,592
  __bf16* a_w    = (__bf16*)(w + 42467328);      // 4,718,592
  __bf16* padb   = (__bf16*)(w + 47185920);      // 19,668,992
  __bf16* wrot   = (__bf16*)(w + 66854912);      // 4,718,592
  __bf16* ya     = (__bf16*)(w + 75497472);      // 18,874,368
  __bf16* yb     = (__bf16*)(w + 94371840);      // 18,874,368
  __bf16* tmp1   = (__bf16*)(w + 113246208);     // 18,874,368
  __bf16* zb     = (__bf16*)(w);                 // 18,874,368 (after attention)
  __bf16* c1wb   = (__bf16*)(w + 132120576);     // 2,097,152
  __bf16* wqkvb  = (__bf16*)(w + 134217728);     // 655,360
  float* qkvbias = (float*)(w + 134873088);      // 2,560
  float* stats   = (float*)(w + 134875648);      // 512

  cast_rot_k<<<512, 256, 0, stream>>>(conv1w, c1wb, 256, 131072);
  wqkv_rot_k<<<160, 256, 0, stream>>>(qw, kw, vw, wqkvb);
  fuse_bias_k<<<3, 256, 0, stream>>>(qbias, kbias, vbias, qkvbias);
  transpose_x_k<<<dim3(32, 144, 2), 256, 0, stream>>>(x, xt);

  {  // conv1: ya = xt @ c1wb^T + b (rotated out)
    GemmAP p{};
    p.A = xt; p.B = c1wb; p.C = ya; p.bias = conv1b;
    p.sAr = 2048; p.sBr = 2048; p.sCr = 512;
    p.K = 2048; p.ntn = 4;
    gemm_async_k<1><<<576, 256, 0, stream>>>(p);
  }

  for (int it = 0; it < 2; it++) {
    __bf16* tin = it ? yb : ya;
    {  // fused qkv projection
      GemmAP p{};
      p.A = tin; p.B = wqkvb; p.C = qkv; p.bias = qkvbias;
      p.sAr = 512; p.sBr = 512; p.sCr = 640;
      p.K = 512; p.ntn = 5;
      gemm_async_k<0><<<720, 256, 0, stream>>>(p);
    }
    cc_scores_k<<<dim3(192, 2), 384, 0, stream>>>(qkv, attnfH, attnfW);
    cc_softmax_k<<<4608, 256, 0, stream>>>(attnfH, attnfW, a_h, a_w);
    {  // agg1: per (b,w): tmp1[b][h][w][c] = sum_i a_h[h,i] * v[b,i,w,c]
      AggP p{};
      p.A = a_h; p.B = qkv + 128; p.C = tmp1;
      p.bB1 = (long long)9216 * 640; p.bB2 = 640; p.sBr = (long long)96 * 640;
      p.cB1 = (long long)9216 * 512; p.cB2 = 512; p.sCr = (long long)96 * 512;
      agg_k<0><<<dim3(4, 1, 192), 256, 0, stream>>>(p);
    }
    {  // agg2 + epilogue: per (b,h)
      AggP p{};
      p.A = a_w; p.B = qkv + 128;
      p.bB1 = (long long)9216 * 640; p.bB2 = (long long)96 * 640; p.sBr = 640;
      p.cB1 = (long long)9216 * 512; p.cB2 = (long long)96 * 512; p.sCr = 512;
      p.tmp = tmp1; p.res = tin; p.gma = gma;
      if (it == 0) {
        p.C = yb;
        agg_k<1><<<dim3(4, 1, 192), 256, 0, stream>>>(p);
      } else {
        p.C = padb;
        agg_k<2><<<dim3(4, 1, 192), 256, 0, stream>>>(p);
      }
    }
  }

  reorder_w_k<<<512, 256, 0, stream>>>(cow, wrot);
  border0_k<<<194, 256, 0, stream>>>(padb);
  conv3_gemm_k<<<576, 256, 0, stream>>>(padb, wrot, zb);
  gn_stats_k<<<64, 256, 0, stream>>>(zb, stats);
  gn_write_k<<<dim3(8, 96, 2), 256, 0, stream>>>(zb, stats, gng, gnb, out);
}